// Round 18
// baseline (85.640 us; speedup 1.0000x reference)
//
#include <hip/hip_runtime.h>
#include <hip/hip_bf16.h>

typedef __attribute__((ext_vector_type(8))) short s16x8;
typedef __attribute__((ext_vector_type(4))) float f32x4;

#define BB 16
#define LL 2048
#define HH 768
#define DD 768
#define MM 8

// d_out layout (float elements)
#define O_LOGITS 0
#define O_BID    128
#define O_LID    256
#define O_AGGL   384
#define O_SCALE  98688
#define O_AGGT   98689

// ws layout (bytes)
#define WTT_OFF  0u          // Wt^T bf16 768*768*2
#define WLT_OFF  1179648u    // Wl^T bf16
#define WTB_OFF  2359296u    // Wt bf16 (natural)
#define HBAR_OFF 3538944u    // 128*768 fp32
#define QH_OFF   3932160u    // 128*768 fp32
#define HST_OFF  4325376u    // 128*768 fp32
#define CVEC_OFF 4718592u    // 128 fp32
#define PML_OFF  4719104u    // 32*16*8*2 fp32 = 32768
#define PO_OFF   4751872u    // 32*16*8*768 fp32 = 12582912
#define SK_OFF   17334784u   // 4*128*768 fp32 (split-K partials, reused)

__device__ __forceinline__ short f2bf(float x) {
  union { float f; unsigned u; } v; v.f = x;
  unsigned r = v.u + 0x7FFFu + ((v.u >> 16) & 1u);
  return (short)(r >> 16);
}

// async global->LDS, 16B per lane; LDS dest is wave-uniform base (HW adds lane*16)
#define GLOAD_LDS16(gp, lp) __builtin_amdgcn_global_load_lds( \
    (const __attribute__((address_space(1))) unsigned int*)(gp), \
    (__attribute__((address_space(3))) unsigned int*)(lp), 16, 0, 0)

// ---------------------------------------------------------------- prep: W converts + hbar (fused)
__global__ void k_prep(const float* __restrict__ Wt, const float* __restrict__ Wl,
                       short* __restrict__ Wtt, short* __restrict__ Wlt,
                       short* __restrict__ Wtb,
                       const float* __restrict__ hs, const int* __restrict__ lmask,
                       float* __restrict__ hbar) {
  __shared__ float tile[64][65];
  __shared__ int list[LL];
  __shared__ int nlist_s;
  int bx = blockIdx.x;
  int t = threadIdx.x;
  if (bx < 432) {
    int z = bx / 144, r = bx % 144;
    int kb = (r % 12) * 64, nb = (r / 12) * 64;
    int c = t & 63;
    int r0 = (t >> 6) * 16;
    if (z == 2) {
#pragma unroll
      for (int i = 0; i < 16; ++i) {
        int rr = kb + r0 + i;
        Wtb[(size_t)rr * DD + nb + c] = f2bf(Wt[(size_t)rr * DD + nb + c]);
      }
      return;
    }
    const float* src = z ? Wl : Wt;
    short* dst = z ? Wlt : Wtt;
#pragma unroll
    for (int i = 0; i < 16; ++i)
      tile[r0 + i][c] = src[(size_t)(kb + r0 + i) * DD + nb + c];
    __syncthreads();
#pragma unroll
    for (int i = 0; i < 16; ++i)
      dst[(size_t)(nb + r0 + i) * HH + kb + c] = f2bf(tile[c][r0 + i]);
    return;
  }
  int bh = bx - 432;
  int b = bh >> 3, m = bh & 7;
  int lane = t & 63, w = t >> 6;
  if (w == 0) {                       // deterministic compaction
    int base = 0;
    for (int win = 0; win < LL / 64; ++win) {
      int l = win * 64 + lane;
      bool match = (lmask[b * LL + l] == m + 1);
      unsigned long long mk = __ballot(match);
      if (match) {
        int pos = base + (int)__popcll(mk & ((1ull << lane) - 1ull));
        list[pos] = l;
      }
      base += (int)__popcll(mk);
    }
    if (lane == 0) nlist_s = base;
  }
  __syncthreads();
  int n = nlist_s;
  float inv = 1.0f / (float)(n > 1 ? n : 1);
  float a0 = 0.f, a1 = 0.f, a2 = 0.f;
  for (int i = 0; i < n; ++i) {
    const float* rr = hs + (size_t)(b * LL + list[i]) * HH;
    a0 += rr[t]; a1 += rr[t + 256]; a2 += rr[t + 512];
  }
  float* dst = hbar + (size_t)(b * MM + m) * HH;
  dst[t] = a0 * inv; dst[t + 256] = a1 * inv; dst[t + 512] = a2 * inv;
}

// ---------------------------------------------------------------- split-K 128x768 GEMM (K=768/4)
// r13-proven LDS-staged body (issue-ahead queue = the latency hiding for
// 24-block grids; direct-fragment regressed — r14/r15 lesson).
__global__ __launch_bounds__(256, 3)
void k_skgemm(const float* __restrict__ A, const short* __restrict__ Bt,
              float* __restrict__ part) {
  __shared__ short As[128][64];
  __shared__ short Bs[2][128][64];
  int t = threadIdx.x;
  int lane = t & 63, w = t >> 6;
  int wm = w >> 1, wn = w & 1;
  int n0 = blockIdx.x * 128;
  int kt0 = blockIdx.y * 3;

  f32x4 acc[4][4] = {};
  float4 areg[8];

  auto issueA = [&](int kt) {
    const float* Ag = A + (size_t)(kt0 + kt) * 64;
#pragma unroll
    for (int i = 0; i < 8; ++i) {
      int slot = i * 256 + t;
      int row = slot >> 4, c = slot & 15;
      areg[i] = *(const float4*)(Ag + (size_t)row * HH + c * 4);
    }
  };
  auto issueB = [&](int kt, int buf) {
    const short* Bg = Bt + (size_t)n0 * HH + (size_t)(kt0 + kt) * 64;
#pragma unroll
    for (int i = 0; i < 4; ++i) {
      int slot = i * 256 + w * 64 + lane;
      int row = slot >> 3, c = slot & 7;
      int cs = c ^ (row & 7);
      GLOAD_LDS16(Bg + (size_t)row * HH + cs * 8,
                  (char*)&Bs[0][0][0] + (size_t)buf * 16384 + (size_t)(i * 256 + w * 64) * 16);
    }
  };
  auto writeA = [&]() {
#pragma unroll
    for (int i = 0; i < 8; ++i) {
      int slot = i * 256 + t;
      int row = slot >> 4, c = slot & 15;
      unsigned d0, d1;
      asm("v_cvt_pk_bf16_f32 %0, %1, %2" : "=v"(d0) : "v"(areg[i].x), "v"(areg[i].y));
      asm("v_cvt_pk_bf16_f32 %0, %1, %2" : "=v"(d1) : "v"(areg[i].z), "v"(areg[i].w));
      int phys = (c >> 1) ^ (row & 7);
      uint2 val = {d0, d1};
      *(uint2*)((char*)&As[0][0] + (size_t)row * 128 + phys * 16 + (c & 1) * 8) = val;
    }
  };
  auto compute = [&](int buf) {
#pragma unroll
    for (int kk = 0; kk < 2; ++kk) {
      s16x8 a[4], bb[4];
#pragma unroll
      for (int i = 0; i < 4; ++i) {
        int row = wm * 64 + i * 16 + (lane & 15);
        int p = (kk * 4 + (lane >> 4)) ^ (row & 7);
        a[i] = *(const s16x8*)((const char*)&As[0][0] + (size_t)row * 128 + p * 16);
      }
#pragma unroll
      for (int i = 0; i < 4; ++i) {
        int row = wn * 64 + i * 16 + (lane & 15);
        int p = (kk * 4 + (lane >> 4)) ^ (row & 7);
        bb[i] = *(const s16x8*)((const char*)&Bs[0][0][0] + (size_t)buf * 16384 + (size_t)row * 128 + p * 16);
      }
#pragma unroll
      for (int mi = 0; mi < 4; ++mi)
#pragma unroll
        for (int ni = 0; ni < 4; ++ni)
          acc[mi][ni] = __builtin_amdgcn_mfma_f32_16x16x32_bf16(a[mi], bb[ni], acc[mi][ni], 0, 0, 0);
    }
  };

  issueA(0); issueB(0, 0);
  writeA();
  __syncthreads();
  for (int kt = 0; kt < 3; ++kt) {
    if (kt + 1 < 3) { issueA(kt + 1); issueB(kt + 1, (kt + 1) & 1); }
    compute(kt & 1);
    __syncthreads();
    if (kt + 1 < 3) {
      writeA();
      __syncthreads();
    }
  }

  float* po = part + (size_t)blockIdx.y * 128 * HH;
#pragma unroll
  for (int mi = 0; mi < 4; ++mi) {
    int row = wm * 64 + mi * 16 + ((lane >> 4) * 4);
#pragma unroll
    for (int ni = 0; ni < 4; ++ni) {
      int col = n0 + wn * 64 + ni * 16 + (lane & 15);
#pragma unroll
      for (int j = 0; j < 4; ++j)
        po[(size_t)(row + j) * HH + col] = acc[mi][ni][j];
    }
  }
}

// ---------------------------------------------------------------- reduce partials -> agg (+bl), cvec
__global__ void k_red_agg(const float* __restrict__ part, const float* __restrict__ bl,
                          const float* __restrict__ bt, float* __restrict__ out,
                          float* __restrict__ cvec) {
  int row = blockIdx.x;
  int t = threadIdx.x;
  int lane = t & 63, w = t >> 6;
  __shared__ float wred[4];
  float dotbt = 0.f;
#pragma unroll
  for (int cc = 0; cc < 3; ++cc) {
    int c = cc * 256 + t;
    float s = bl[c];
#pragma unroll
    for (int kc = 0; kc < 4; ++kc)
      s += part[((size_t)kc * 128 + row) * HH + c];
    out[O_AGGL + (size_t)row * DD + c] = s;
    dotbt += s * bt[c];
  }
  for (int sh = 32; sh; sh >>= 1) dotbt += __shfl_xor(dotbt, sh, 64);
  if (lane == 0) wred[w] = dotbt;
  __syncthreads();
  if (t == 0) cvec[row] = wred[0] + wred[1] + wred[2] + wred[3];
}

// ---------------------------------------------------------------- reduce partials -> qh
__global__ void k_red_qh(const float* __restrict__ part, float* __restrict__ qh) {
  int row = blockIdx.x;
  int t = threadIdx.x;
#pragma unroll
  for (int cc = 0; cc < 3; ++cc) {
    int c = cc * 256 + t;
    float s = 0.f;
#pragma unroll
    for (int kc = 0; kc < 4; ++kc)
      s += part[((size_t)kc * 128 + row) * HH + c];
    qh[(size_t)row * HH + c] = s;
  }
}

// ---------------------------------------------------------------- fused scores+softmax-partial+pool
// Phase 1: barrier-free wave-private staging with PREFETCH DEPTH 3 — three
// areg sets + three LDS buffers per wave; every vmcnt wait lands ~2 compute
// phases after issue (r17 lesson: depth-1 left waves stalled ~800cy/K-step).
__global__ __launch_bounds__(256, 2)
void k_attnpool(const float* __restrict__ hs, const float* __restrict__ qh,
                const float* __restrict__ cvec, const int* __restrict__ lmask,
                const int* __restrict__ amask, const float* __restrict__ temp_p,
                float* __restrict__ part_o, float* __restrict__ part_ml) {
  __shared__ short As[4][3][16][64]; // wave-private triple buffers, 24 KB
  __shared__ short Bs[16][776];      // 24.8 KB (rows 8..15 zero)
  __shared__ float w_lds[64][8];     // 2 KB
  int chunk = blockIdx.x;            // 32
  int b = blockIdx.y;                // 16
  int t = threadIdx.x;
  int lane = t & 63, w = t >> 6;

  const float* qsrc = qh + (size_t)b * MM * HH;
  for (int c = t; c < HH; c += 256) {
#pragma unroll
    for (int r = 0; r < 8; ++r) Bs[r][c] = f2bf(qsrc[(size_t)r * HH + c]);
#pragma unroll
    for (int r = 8; r < 16; ++r) Bs[r][c] = 0;
  }

  const float* Hg = hs + (size_t)(b * LL + chunk * 64) * HH;
  const float* Wrow = Hg + (size_t)(w * 16) * HH;   // this wave's 16 token rows
  float4 areg[3][4];                  // 3 in-flight tiles (static indices only)

  f32x4 acc = {};
  // prologue: issue tiles 0..2 (12 loads in flight per wave)
#pragma unroll
  for (int d = 0; d < 3; ++d) {
#pragma unroll
    for (int i = 0; i < 4; ++i) {
      int slot = i * 64 + lane;
      int row = slot >> 4, c = slot & 15;
      areg[d][i] = *(const float4*)(Wrow + (size_t)row * HH + d * 64 + c * 4);
    }
  }
  // write tile 0
#pragma unroll
  for (int i = 0; i < 4; ++i) {
    int slot = i * 64 + lane;
    int row = slot >> 4, c = slot & 15;
    unsigned d0, d1;
    asm("v_cvt_pk_bf16_f32 %0, %1, %2" : "=v"(d0) : "v"(areg[0][i].x), "v"(areg[0][i].y));
    asm("v_cvt_pk_bf16_f32 %0, %1, %2" : "=v"(d1) : "v"(areg[0][i].z), "v"(areg[0][i].w));
    int phys = (c >> 1) ^ (row & 7);
    uint2 val = {d0, d1};
    *(uint2*)((char*)&As[w][0][0][0] + (size_t)row * 128 + phys * 16 + (c & 1) * 8) = val;
  }
  __syncthreads();                     // Bs visible (As slices wave-private)

#pragma unroll
  for (int kt = 0; kt < 12; ++kt) {
    int buf = kt % 3;
#pragma unroll
    for (int kk = 0; kk < 2; ++kk) {
      int r = lane & 15;
      int p = (kk * 4 + (lane >> 4)) ^ (r & 7);
      s16x8 a = *(const s16x8*)((const char*)&As[w][buf][0][0] + (size_t)r * 128 + p * 16);
      s16x8 bfr = *(const s16x8*)&Bs[lane & 15][kt * 64 + kk * 32 + (lane >> 4) * 8];
      acc = __builtin_amdgcn_mfma_f32_16x16x32_bf16(a, bfr, acc, 0, 0, 0);
    }
    if (kt + 1 < 12) {                 // write tile kt+1 (issued >=2 iters ago)
      int nb = (kt + 1) % 3;
#pragma unroll
      for (int i = 0; i < 4; ++i) {
        int slot = i * 64 + lane;
        int row = slot >> 4, c = slot & 15;
        unsigned d0, d1;
        asm("v_cvt_pk_bf16_f32 %0, %1, %2" : "=v"(d0) : "v"(areg[(kt + 1) % 3][i].x), "v"(areg[(kt + 1) % 3][i].y));
        asm("v_cvt_pk_bf16_f32 %0, %1, %2" : "=v"(d1) : "v"(areg[(kt + 1) % 3][i].z), "v"(areg[(kt + 1) % 3][i].w));
        int phys = (c >> 1) ^ (row & 7);
        uint2 val = {d0, d1};
        *(uint2*)((char*)&As[w][nb][0][0] + (size_t)row * 128 + phys * 16 + (c & 1) * 8) = val;
      }
    }
    if (kt + 3 < 12) {                 // issue tile kt+3 into freed areg set
#pragma unroll
      for (int i = 0; i < 4; ++i) {
        int slot = i * 64 + lane;
        int row = slot >> 4, c = slot & 15;
        areg[(kt + 3) % 3][i] = *(const float4*)(Wrow + (size_t)row * HH + (kt + 3) * 64 + c * 4);
      }
    }
  }

  // epilogue -> s in LDS
  float inv_temp = 1.0f / fmaxf(fabsf(temp_p[0]), 0.1f);
  int m = lane & 15;
  int tok0 = w * 16 + (lane >> 4) * 4;
  if (m < MM) {
    float cv = cvec[b * MM + m];
    int4 lm = *(const int4*)&lmask[b * LL + chunk * 64 + tok0];
    int4 am = *(const int4*)&amask[b * LL + chunk * 64 + tok0];
    w_lds[tok0 + 0][m] = (lm.x == 0 && am.x == 1) ? (acc[0] + cv) * inv_temp : -1e30f;
    w_lds[tok0 + 1][m] = (lm.y == 0 && am.y == 1) ? (acc[1] + cv) * inv_temp : -1e30f;
    w_lds[tok0 + 2][m] = (lm.z == 0 && am.z == 1) ? (acc[2] + cv) * inv_temp : -1e30f;
    w_lds[tok0 + 3][m] = (lm.w == 0 && am.w == 1) ? (acc[3] + cv) * inv_temp : -1e30f;
  }
  __syncthreads();

  // Phase 2: wave w handles m = w and m = w+4 (one token per lane)
#pragma unroll
  for (int half = 0; half < 2; ++half) {
    int mm = w + half * 4;
    float v = w_lds[lane][mm];
    float mx = v;
    for (int s = 32; s; s >>= 1) mx = fmaxf(mx, __shfl_xor(mx, s, 64));
    float e = __expf(v - mx);
    float l = e;
    for (int s = 32; s; s >>= 1) l += __shfl_xor(l, s, 64);
    w_lds[lane][mm] = e;
    if (lane == 0) {
      float* pml = part_ml + ((size_t)(chunk * BB + b) * MM + mm) * 2;
      pml[0] = mx; pml[1] = l;
    }
  }
  __syncthreads();

  // Phase 3: partial pool; threads 0..191 own 4 h-cols each (hs re-read, L2-hot)
  if (t < 192) {
    int h0 = t * 4;
    f32x4 o[8] = {};
    const float* hp = Hg + h0;
    for (int tok = 0; tok < 64; ++tok) {
      float4 hv = *(const float4*)(hp + (size_t)tok * HH);
      float4 w0 = *(const float4*)&w_lds[tok][0];
      float4 w1 = *(const float4*)&w_lds[tok][4];
      o[0][0] += w0.x * hv.x; o[0][1] += w0.x * hv.y; o[0][2] += w0.x * hv.z; o[0][3] += w0.x * hv.w;
      o[1][0] += w0.y * hv.x; o[1][1] += w0.y * hv.y; o[1][2] += w0.y * hv.z; o[1][3] += w0.y * hv.w;
      o[2][0] += w0.z * hv.x; o[2][1] += w0.z * hv.y; o[2][2] += w0.z * hv.z; o[2][3] += w0.z * hv.w;
      o[3][0] += w0.w * hv.x; o[3][1] += w0.w * hv.y; o[3][2] += w0.w * hv.z; o[3][3] += w0.w * hv.w;
      o[4][0] += w1.x * hv.x; o[4][1] += w1.x * hv.y; o[4][2] += w1.x * hv.z; o[4][3] += w1.x * hv.w;
      o[5][0] += w1.y * hv.x; o[5][1] += w1.y * hv.y; o[5][2] += w1.y * hv.z; o[5][3] += w1.y * hv.w;
      o[6][0] += w1.z * hv.x; o[6][1] += w1.z * hv.y; o[6][2] += w1.z * hv.z; o[6][3] += w1.z * hv.w;
      o[7][0] += w1.w * hv.x; o[7][1] += w1.w * hv.y; o[7][2] += w1.w * hv.z; o[7][3] += w1.w * hv.w;
    }
    float* po = part_o + (size_t)(chunk * BB + b) * MM * HH + h0;
#pragma unroll
    for (int mm = 0; mm < 8; ++mm)
      *(f32x4*)(po + (size_t)mm * HH) = o[mm];
  }
}

// ---------------------------------------------------------------- finish: flash-reduce partials -> hst
__global__ void k_finish(const float* __restrict__ part_o, const float* __restrict__ part_ml,
                         float* __restrict__ hst) {
  int row = blockIdx.x;
  int b = row >> 3, m = row & 7;
  int t = threadIdx.x;     // 192
  float mg = -1e30f;
#pragma unroll
  for (int lc = 0; lc < 32; ++lc)
    mg = fmaxf(mg, part_ml[((size_t)(lc * BB + b) * MM + m) * 2]);
  float L = 0.f;
  f32x4 acc = {};
  int h0 = t * 4;
  for (int lc = 0; lc < 32; ++lc) {
    const float* pml = part_ml + ((size_t)(lc * BB + b) * MM + m) * 2;
    float f = __expf(pml[0] - mg);
    L += pml[1] * f;
    f32x4 v = *(const f32x4*)(part_o + ((size_t)(lc * BB + b) * MM + m) * HH + h0);
    acc[0] += v[0] * f; acc[1] += v[1] * f; acc[2] += v[2] * f; acc[3] += v[3] * f;
  }
  float inv = 1.0f / L;
  f32x4 r = {acc[0] * inv, acc[1] * inv, acc[2] * inv, acc[3] * inv};
  *(f32x4*)(hst + (size_t)row * HH + h0) = r;
}

// ---------------------------------------------------------------- head: aggt reduce + write + cosine
__global__ void k_head(const float* __restrict__ part, const float* __restrict__ bt,
                       const float* __restrict__ lscale_p, float* __restrict__ out) {
  int row = blockIdx.x;   // 128
  int lane = threadIdx.x; // 64
  const float* al = out + O_AGGL + (size_t)row * DD;
  float dot = 0.f, nt = 0.f, nl = 0.f;
  for (int i = lane; i < DD; i += 64) {
    float a = bt[i];
#pragma unroll
    for (int kc = 0; kc < 4; ++kc)
      a += part[((size_t)kc * 128 + row) * HH + i];
    out[O_AGGT + (size_t)row * DD + i] = a;
    float c = al[i];
    dot += a * c; nt += a * a; nl += c * c;
  }
  for (int s = 32; s; s >>= 1) {
    dot += __shfl_xor(dot, s, 64);
    nt  += __shfl_xor(nt, s, 64);
    nl  += __shfl_xor(nl, s, 64);
  }
  if (lane == 0) {
    float scale = expf(lscale_p[0]);
    float denom = fmaxf(sqrtf(nt), 1e-8f) * fmaxf(sqrtf(nl), 1e-8f);
    out[O_LOGITS + row] = dot / denom * scale;
    out[O_BID + row] = (float)(row >> 3);
    out[O_LID + row] = (float)((row & 7) + 1);
    if (row == 0) out[O_SCALE] = scale;
  }
}

extern "C" void kernel_launch(void* const* d_in, const int* in_sizes, int n_in,
                              void* d_out, int out_size, void* d_ws, size_t ws_size,
                              hipStream_t stream) {
  const float* hs    = (const float*)d_in[0];
  const float* Wt    = (const float*)d_in[1];
  const float* bt    = (const float*)d_in[2];
  const float* Wl    = (const float*)d_in[3];
  const float* bl    = (const float*)d_in[4];
  const float* atemp = (const float*)d_in[5];
  const float* lsc   = (const float*)d_in[6];
  const int*   lmask = (const int*)d_in[7];
  const int*   amask = (const int*)d_in[9];
  float* out = (float*)d_out;
  char* ws = (char*)d_ws;
  short* Wtt  = (short*)(ws + WTT_OFF);
  short* Wlt  = (short*)(ws + WLT_OFF);
  short* Wtb  = (short*)(ws + WTB_OFF);
  float* hbar = (float*)(ws + HBAR_OFF);
  float* qh   = (float*)(ws + QH_OFF);
  float* hst  = (float*)(ws + HST_OFF);
  float* cvec = (float*)(ws + CVEC_OFF);
  float* pml  = (float*)(ws + PML_OFF);
  float* po   = (float*)(ws + PO_OFF);
  float* skp  = (float*)(ws + SK_OFF);

  k_prep<<<560, 256, 0, stream>>>(Wt, Wl, Wtt, Wlt, Wtb, hs, lmask, hbar);
  k_skgemm<<<dim3(6, 4), 256, 0, stream>>>(hbar, Wlt, skp);
  k_red_agg<<<128, 256, 0, stream>>>(skp, bl, bt, out, cvec);
  k_skgemm<<<dim3(6, 4), 256, 0, stream>>>(out + O_AGGL, Wtb, skp);
  k_red_qh<<<128, 256, 0, stream>>>(skp, qh);
  k_attnpool<<<dim3(32, 16), 256, 0, stream>>>(hs, qh, cvec, lmask, amask, atemp, po, pml);
  k_finish<<<128, 192, 0, stream>>>(po, pml, hst);
  k_skgemm<<<dim3(6, 4), 256, 0, stream>>>(hst, Wtt, skp);
  k_head<<<128, 64, 0, stream>>>(skp, bt, lsc, out);
}

// Round 19
// 84.470 us; speedup vs baseline: 1.0139x; 1.0139x over previous
//
#include <hip/hip_runtime.h>
#include <hip/hip_bf16.h>

typedef __attribute__((ext_vector_type(8))) short s16x8;
typedef __attribute__((ext_vector_type(4))) float f32x4;

#define BB 16
#define LL 2048
#define HH 768
#define DD 768
#define MM 8

// d_out layout (float elements)
#define O_LOGITS 0
#define O_BID    128
#define O_LID    256
#define O_AGGL   384
#define O_SCALE  98688
#define O_AGGT   98689

// ws layout (bytes)
#define WTT_OFF  0u          // Wt^T bf16 768*768*2
#define WLT_OFF  1179648u    // Wl^T bf16
#define WTB_OFF  2359296u    // Wt bf16 (natural)
#define HBAR_OFF 3538944u    // 128*768 fp32
#define QH_OFF   3932160u    // (unused)
#define HST_OFF  4325376u    // 128*768 fp32
#define CVEC_OFF 4718592u    // 128 fp32
#define PML_OFF  4719104u    // 32*16*8*2 fp32 = 32768
#define PO_OFF   4751872u    // 32*16*8*768 fp32 = 12582912
#define SK_OFF   17334784u   // 4*128*768 fp32 (split-K partials, reused)

__device__ __forceinline__ short f2bf(float x) {
  union { float f; unsigned u; } v; v.f = x;
  unsigned r = v.u + 0x7FFFu + ((v.u >> 16) & 1u);
  return (short)(r >> 16);
}

// async global->LDS, 16B per lane; LDS dest is wave-uniform base (HW adds lane*16)
#define GLOAD_LDS16(gp, lp) __builtin_amdgcn_global_load_lds( \
    (const __attribute__((address_space(1))) unsigned int*)(gp), \
    (__attribute__((address_space(3))) unsigned int*)(lp), 16, 0, 0)

// ---------------------------------------------------------------- prep: W converts + hbar (fused)
__global__ void k_prep(const float* __restrict__ Wt, const float* __restrict__ Wl,
                       short* __restrict__ Wtt, short* __restrict__ Wlt,
                       short* __restrict__ Wtb,
                       const float* __restrict__ hs, const int* __restrict__ lmask,
                       float* __restrict__ hbar) {
  __shared__ float tile[64][65];
  __shared__ int list[LL];
  __shared__ int nlist_s;
  int bx = blockIdx.x;
  int t = threadIdx.x;
  if (bx < 432) {
    int z = bx / 144, r = bx % 144;
    int kb = (r % 12) * 64, nb = (r / 12) * 64;
    int c = t & 63;
    int r0 = (t >> 6) * 16;
    if (z == 2) {
#pragma unroll
      for (int i = 0; i < 16; ++i) {
        int rr = kb + r0 + i;
        Wtb[(size_t)rr * DD + nb + c] = f2bf(Wt[(size_t)rr * DD + nb + c]);
      }
      return;
    }
    const float* src = z ? Wl : Wt;
    short* dst = z ? Wlt : Wtt;
#pragma unroll
    for (int i = 0; i < 16; ++i)
      tile[r0 + i][c] = src[(size_t)(kb + r0 + i) * DD + nb + c];
    __syncthreads();
#pragma unroll
    for (int i = 0; i < 16; ++i)
      dst[(size_t)(nb + r0 + i) * HH + kb + c] = f2bf(tile[c][r0 + i]);
    return;
  }
  int bh = bx - 432;
  int b = bh >> 3, m = bh & 7;
  int lane = t & 63, w = t >> 6;
  if (w == 0) {                       // deterministic compaction
    int base = 0;
    for (int win = 0; win < LL / 64; ++win) {
      int l = win * 64 + lane;
      bool match = (lmask[b * LL + l] == m + 1);
      unsigned long long mk = __ballot(match);
      if (match) {
        int pos = base + (int)__popcll(mk & ((1ull << lane) - 1ull));
        list[pos] = l;
      }
      base += (int)__popcll(mk);
    }
    if (lane == 0) nlist_s = base;
  }
  __syncthreads();
  int n = nlist_s;
  float inv = 1.0f / (float)(n > 1 ? n : 1);
  float a0 = 0.f, a1 = 0.f, a2 = 0.f;
  for (int i = 0; i < n; ++i) {
    const float* rr = hs + (size_t)(b * LL + list[i]) * HH;
    a0 += rr[t]; a1 += rr[t + 256]; a2 += rr[t + 512];
  }
  float* dst = hbar + (size_t)(b * MM + m) * HH;
  dst[t] = a0 * inv; dst[t + 256] = a1 * inv; dst[t + 512] = a2 * inv;
}

// ---------------------------------------------------------------- split-K 128x768 GEMM (K=768/4)
// r13-proven LDS-staged body (issue-ahead queue = the latency hiding for
// 24-block grids; direct-fragment regressed — r14/r15 lesson).
__global__ __launch_bounds__(256, 3)
void k_skgemm(const float* __restrict__ A, const short* __restrict__ Bt,
              float* __restrict__ part) {
  __shared__ short As[128][64];
  __shared__ short Bs[2][128][64];
  int t = threadIdx.x;
  int lane = t & 63, w = t >> 6;
  int wm = w >> 1, wn = w & 1;
  int n0 = blockIdx.x * 128;
  int kt0 = blockIdx.y * 3;

  f32x4 acc[4][4] = {};
  float4 areg[8];

  auto issueA = [&](int kt) {
    const float* Ag = A + (size_t)(kt0 + kt) * 64;
#pragma unroll
    for (int i = 0; i < 8; ++i) {
      int slot = i * 256 + t;
      int row = slot >> 4, c = slot & 15;
      areg[i] = *(const float4*)(Ag + (size_t)row * HH + c * 4);
    }
  };
  auto issueB = [&](int kt, int buf) {
    const short* Bg = Bt + (size_t)n0 * HH + (size_t)(kt0 + kt) * 64;
#pragma unroll
    for (int i = 0; i < 4; ++i) {
      int slot = i * 256 + w * 64 + lane;
      int row = slot >> 3, c = slot & 7;
      int cs = c ^ (row & 7);
      GLOAD_LDS16(Bg + (size_t)row * HH + cs * 8,
                  (char*)&Bs[0][0][0] + (size_t)buf * 16384 + (size_t)(i * 256 + w * 64) * 16);
    }
  };
  auto writeA = [&]() {
#pragma unroll
    for (int i = 0; i < 8; ++i) {
      int slot = i * 256 + t;
      int row = slot >> 4, c = slot & 15;
      unsigned d0, d1;
      asm("v_cvt_pk_bf16_f32 %0, %1, %2" : "=v"(d0) : "v"(areg[i].x), "v"(areg[i].y));
      asm("v_cvt_pk_bf16_f32 %0, %1, %2" : "=v"(d1) : "v"(areg[i].z), "v"(areg[i].w));
      int phys = (c >> 1) ^ (row & 7);
      uint2 val = {d0, d1};
      *(uint2*)((char*)&As[0][0] + (size_t)row * 128 + phys * 16 + (c & 1) * 8) = val;
    }
  };
  auto compute = [&](int buf) {
#pragma unroll
    for (int kk = 0; kk < 2; ++kk) {
      s16x8 a[4], bb[4];
#pragma unroll
      for (int i = 0; i < 4; ++i) {
        int row = wm * 64 + i * 16 + (lane & 15);
        int p = (kk * 4 + (lane >> 4)) ^ (row & 7);
        a[i] = *(const s16x8*)((const char*)&As[0][0] + (size_t)row * 128 + p * 16);
      }
#pragma unroll
      for (int i = 0; i < 4; ++i) {
        int row = wn * 64 + i * 16 + (lane & 15);
        int p = (kk * 4 + (lane >> 4)) ^ (row & 7);
        bb[i] = *(const s16x8*)((const char*)&Bs[0][0][0] + (size_t)buf * 16384 + (size_t)row * 128 + p * 16);
      }
#pragma unroll
      for (int mi = 0; mi < 4; ++mi)
#pragma unroll
        for (int ni = 0; ni < 4; ++ni)
          acc[mi][ni] = __builtin_amdgcn_mfma_f32_16x16x32_bf16(a[mi], bb[ni], acc[mi][ni], 0, 0, 0);
    }
  };

  issueA(0); issueB(0, 0);
  writeA();
  __syncthreads();
  for (int kt = 0; kt < 3; ++kt) {
    if (kt + 1 < 3) { issueA(kt + 1); issueB(kt + 1, (kt + 1) & 1); }
    compute(kt & 1);
    __syncthreads();
    if (kt + 1 < 3) {
      writeA();
      __syncthreads();
    }
  }

  float* po = part + (size_t)blockIdx.y * 128 * HH;
#pragma unroll
  for (int mi = 0; mi < 4; ++mi) {
    int row = wm * 64 + mi * 16 + ((lane >> 4) * 4);
#pragma unroll
    for (int ni = 0; ni < 4; ++ni) {
      int col = n0 + wn * 64 + ni * 16 + (lane & 15);
#pragma unroll
      for (int j = 0; j < 4; ++j)
        po[(size_t)(row + j) * HH + col] = acc[mi][ni][j];
    }
  }
}

// ---------------------------------------------------------------- reduce partials -> agg (+bl), cvec
__global__ void k_red_agg(const float* __restrict__ part, const float* __restrict__ bl,
                          const float* __restrict__ bt, float* __restrict__ out,
                          float* __restrict__ cvec) {
  int row = blockIdx.x;
  int t = threadIdx.x;
  int lane = t & 63, w = t >> 6;
  __shared__ float wred[4];
  float dotbt = 0.f;
#pragma unroll
  for (int cc = 0; cc < 3; ++cc) {
    int c = cc * 256 + t;
    float s = bl[c];
#pragma unroll
    for (int kc = 0; kc < 4; ++kc)
      s += part[((size_t)kc * 128 + row) * HH + c];
    out[O_AGGL + (size_t)row * DD + c] = s;
    dotbt += s * bt[c];
  }
  for (int sh = 32; sh; sh >>= 1) dotbt += __shfl_xor(dotbt, sh, 64);
  if (lane == 0) wred[w] = dotbt;
  __syncthreads();
  if (t == 0) cvec[row] = wred[0] + wred[1] + wred[2] + wred[3];
}

// ---------------------------------------------------------------- fused scores+softmax-partial+pool
// SPLIT-K phase 1 (16 waves/CU): 8 waves; wave pair (wq, wq+4) computes K-half
// of the same 16 tokens. Wave-private double-buffered As (barrier-free staging,
// r17); partial accs combined via disjoint-slot LDS + barrier. qh 4-partial
// reduce folded into Bs staging (deletes k_red_qh). Phase 2: 1 m per wave.
// Phase 3: 384 threads x 2 cols.
__global__ __launch_bounds__(512, 4)
void k_attnpool(const float* __restrict__ hs, const float* __restrict__ qhp,
                const float* __restrict__ cvec, const int* __restrict__ lmask,
                const int* __restrict__ amask, const float* __restrict__ temp_p,
                float* __restrict__ part_o, float* __restrict__ part_ml) {
  __shared__ short As[8][2][16][64];  // wave-private double buffers, 32 KB
  __shared__ short Bs[16][776];       // 24.8 KB (rows 8..15 zero)
  __shared__ float w_acc[4][64][4];   // 4 KB split-K combine
  __shared__ float w_lds[64][8];      // 2 KB
  int chunk = blockIdx.x;             // 32
  int b = blockIdx.y;                 // 16
  int t = threadIdx.x;
  int lane = t & 63, w = t >> 6;      // w 0..7
  int wq = w & 3, kw = w >> 2;        // token quad, K-half

  // stage qh = sum of 4 split-K partials (L2-hot), bf16; rows 8..15 zero
  for (int c = t; c < HH; c += 512) {
#pragma unroll
    for (int r = 0; r < 8; ++r) {
      size_t o = (size_t)(b * MM + r) * HH + c;
      float s = qhp[o] + qhp[(size_t)128 * HH + o] + qhp[(size_t)256 * HH + o] + qhp[(size_t)384 * HH + o];
      Bs[r][c] = f2bf(s);
    }
#pragma unroll
    for (int r = 8; r < 16; ++r) Bs[r][c] = 0;
  }

  const float* Hg = hs + (size_t)(b * LL + chunk * 64) * HH;
  const float* Wrow = Hg + (size_t)(wq * 16) * HH;   // this wave's 16 token rows
  int kbase = kw * 384;                              // this wave's K-half
  float4 areg[2][4];

  auto issueA = [&](int set, int kt) {
#pragma unroll
    for (int i = 0; i < 4; ++i) {
      int slot = i * 64 + lane;
      int row = slot >> 4, c = slot & 15;
      if (set == 0)
        areg[0][i] = *(const float4*)(Wrow + (size_t)row * HH + kbase + kt * 64 + c * 4);
      else
        areg[1][i] = *(const float4*)(Wrow + (size_t)row * HH + kbase + kt * 64 + c * 4);
    }
  };
  auto writeA = [&](int set, int buf) {
#pragma unroll
    for (int i = 0; i < 4; ++i) {
      int slot = i * 64 + lane;
      int row = slot >> 4, c = slot & 15;
      float4 v = set == 0 ? areg[0][i] : areg[1][i];
      unsigned d0, d1;
      asm("v_cvt_pk_bf16_f32 %0, %1, %2" : "=v"(d0) : "v"(v.x), "v"(v.y));
      asm("v_cvt_pk_bf16_f32 %0, %1, %2" : "=v"(d1) : "v"(v.z), "v"(v.w));
      int phys = (c >> 1) ^ (row & 7);
      uint2 val = {d0, d1};
      *(uint2*)((char*)&As[w][buf][0][0] + (size_t)row * 128 + phys * 16 + (c & 1) * 8) = val;
    }
  };

  f32x4 acc = {};
  issueA(0, 0); issueA(1, 1);
  writeA(0, 0);
  __syncthreads();                     // Bs visible (As slices wave-private)
#pragma unroll
  for (int kt = 0; kt < 6; ++kt) {
    int buf = kt & 1;
#pragma unroll
    for (int kk = 0; kk < 2; ++kk) {
      int r = lane & 15;
      int p = (kk * 4 + (lane >> 4)) ^ (r & 7);
      s16x8 a = *(const s16x8*)((const char*)&As[w][buf][0][0] + (size_t)r * 128 + p * 16);
      s16x8 bfr = *(const s16x8*)&Bs[lane & 15][kbase + kt * 64 + kk * 32 + (lane >> 4) * 8];
      acc = __builtin_amdgcn_mfma_f32_16x16x32_bf16(a, bfr, acc, 0, 0, 0);
    }
    if (kt + 1 < 6) writeA((kt + 1) & 1, (kt + 1) & 1);
    if (kt + 2 < 6) issueA(kt & 1, kt + 2);
  }

  // combine K-halves: waves 4..7 deposit, waves 0..3 add
  if (kw == 1) {
    w_acc[wq][lane][0] = acc[0]; w_acc[wq][lane][1] = acc[1];
    w_acc[wq][lane][2] = acc[2]; w_acc[wq][lane][3] = acc[3];
  }
  __syncthreads();
  if (kw == 0) {
    acc[0] += w_acc[wq][lane][0]; acc[1] += w_acc[wq][lane][1];
    acc[2] += w_acc[wq][lane][2]; acc[3] += w_acc[wq][lane][3];
  }

  // epilogue (waves 0..3) -> s in LDS
  float inv_temp = 1.0f / fmaxf(fabsf(temp_p[0]), 0.1f);
  int m = lane & 15;
  int tok0 = wq * 16 + (lane >> 4) * 4;
  if (kw == 0 && m < MM) {
    float cv = cvec[b * MM + m];
    int4 lm = *(const int4*)&lmask[b * LL + chunk * 64 + tok0];
    int4 am = *(const int4*)&amask[b * LL + chunk * 64 + tok0];
    w_lds[tok0 + 0][m] = (lm.x == 0 && am.x == 1) ? (acc[0] + cv) * inv_temp : -1e30f;
    w_lds[tok0 + 1][m] = (lm.y == 0 && am.y == 1) ? (acc[1] + cv) * inv_temp : -1e30f;
    w_lds[tok0 + 2][m] = (lm.z == 0 && am.z == 1) ? (acc[2] + cv) * inv_temp : -1e30f;
    w_lds[tok0 + 3][m] = (lm.w == 0 && am.w == 1) ? (acc[3] + cv) * inv_temp : -1e30f;
  }
  __syncthreads();

  // Phase 2: wave w handles m = w (one token per lane, single pass)
  {
    float v = w_lds[lane][w];
    float mx = v;
    for (int s = 32; s; s >>= 1) mx = fmaxf(mx, __shfl_xor(mx, s, 64));
    float e = __expf(v - mx);
    float l = e;
    for (int s = 32; s; s >>= 1) l += __shfl_xor(l, s, 64);
    w_lds[lane][w] = e;
    if (lane == 0) {
      float* pml = part_ml + ((size_t)(chunk * BB + b) * MM + w) * 2;
      pml[0] = mx; pml[1] = l;
    }
  }
  __syncthreads();

  // Phase 3: partial pool; threads 0..383 own 2 h-cols each (hs re-read, L2-hot)
  if (t < 384) {
    int h0 = t * 2;
    float2 o[8] = {};
    const float* hp = Hg + h0;
    for (int tok = 0; tok < 64; ++tok) {
      float2 hv = *(const float2*)(hp + (size_t)tok * HH);
      float4 w0 = *(const float4*)&w_lds[tok][0];
      float4 w1 = *(const float4*)&w_lds[tok][4];
      o[0].x += w0.x * hv.x; o[0].y += w0.x * hv.y;
      o[1].x += w0.y * hv.x; o[1].y += w0.y * hv.y;
      o[2].x += w0.z * hv.x; o[2].y += w0.z * hv.y;
      o[3].x += w0.w * hv.x; o[3].y += w0.w * hv.y;
      o[4].x += w1.x * hv.x; o[4].y += w1.x * hv.y;
      o[5].x += w1.y * hv.x; o[5].y += w1.y * hv.y;
      o[6].x += w1.z * hv.x; o[6].y += w1.z * hv.y;
      o[7].x += w1.w * hv.x; o[7].y += w1.w * hv.y;
    }
    float* po = part_o + (size_t)(chunk * BB + b) * MM * HH + h0;
#pragma unroll
    for (int mm = 0; mm < 8; ++mm)
      *(float2*)(po + (size_t)mm * HH) = o[mm];
  }
}

// ---------------------------------------------------------------- finish: flash-reduce partials -> hst
__global__ void k_finish(const float* __restrict__ part_o, const float* __restrict__ part_ml,
                         float* __restrict__ hst) {
  int row = blockIdx.x;
  int b = row >> 3, m = row & 7;
  int t = threadIdx.x;     // 192
  float mg = -1e30f;
#pragma unroll
  for (int lc = 0; lc < 32; ++lc)
    mg = fmaxf(mg, part_ml[((size_t)(lc * BB + b) * MM + m) * 2]);
  float L = 0.f;
  f32x4 acc = {};
  int h0 = t * 4;
  for (int lc = 0; lc < 32; ++lc) {
    const float* pml = part_ml + ((size_t)(lc * BB + b) * MM + m) * 2;
    float f = __expf(pml[0] - mg);
    L += pml[1] * f;
    f32x4 v = *(const f32x4*)(part_o + ((size_t)(lc * BB + b) * MM + m) * HH + h0);
    acc[0] += v[0] * f; acc[1] += v[1] * f; acc[2] += v[2] * f; acc[3] += v[3] * f;
  }
  float inv = 1.0f / L;
  f32x4 r = {acc[0] * inv, acc[1] * inv, acc[2] * inv, acc[3] * inv};
  *(f32x4*)(hst + (size_t)row * HH + h0) = r;
}

// ---------------------------------------------------------------- head: aggt reduce + write + cosine
__global__ void k_head(const float* __restrict__ part, const float* __restrict__ bt,
                       const float* __restrict__ lscale_p, float* __restrict__ out) {
  int row = blockIdx.x;   // 128
  int lane = threadIdx.x; // 64
  const float* al = out + O_AGGL + (size_t)row * DD;
  float dot = 0.f, nt = 0.f, nl = 0.f;
  for (int i = lane; i < DD; i += 64) {
    float a = bt[i];
#pragma unroll
    for (int kc = 0; kc < 4; ++kc)
      a += part[((size_t)kc * 128 + row) * HH + i];
    out[O_AGGT + (size_t)row * DD + i] = a;
    float c = al[i];
    dot += a * c; nt += a * a; nl += c * c;
  }
  for (int s = 32; s; s >>= 1) {
    dot += __shfl_xor(dot, s, 64);
    nt  += __shfl_xor(nt, s, 64);
    nl  += __shfl_xor(nl, s, 64);
  }
  if (lane == 0) {
    float scale = expf(lscale_p[0]);
    float denom = fmaxf(sqrtf(nt), 1e-8f) * fmaxf(sqrtf(nl), 1e-8f);
    out[O_LOGITS + row] = dot / denom * scale;
    out[O_BID + row] = (float)(row >> 3);
    out[O_LID + row] = (float)((row & 7) + 1);
    if (row == 0) out[O_SCALE] = scale;
  }
}

extern "C" void kernel_launch(void* const* d_in, const int* in_sizes, int n_in,
                              void* d_out, int out_size, void* d_ws, size_t ws_size,
                              hipStream_t stream) {
  const float* hs    = (const float*)d_in[0];
  const float* Wt    = (const float*)d_in[1];
  const float* bt    = (const float*)d_in[2];
  const float* Wl    = (const float*)d_in[3];
  const float* bl    = (const float*)d_in[4];
  const float* atemp = (const float*)d_in[5];
  const float* lsc   = (const float*)d_in[6];
  const int*   lmask = (const int*)d_in[7];
  const int*   amask = (const int*)d_in[9];
  float* out = (float*)d_out;
  char* ws = (char*)d_ws;
  short* Wtt  = (short*)(ws + WTT_OFF);
  short* Wlt  = (short*)(ws + WLT_OFF);
  short* Wtb  = (short*)(ws + WTB_OFF);
  float* hbar = (float*)(ws + HBAR_OFF);
  float* hst  = (float*)(ws + HST_OFF);
  float* cvec = (float*)(ws + CVEC_OFF);
  float* pml  = (float*)(ws + PML_OFF);
  float* po   = (float*)(ws + PO_OFF);
  float* skp  = (float*)(ws + SK_OFF);

  k_prep<<<560, 256, 0, stream>>>(Wt, Wl, Wtt, Wlt, Wtb, hs, lmask, hbar);
  k_skgemm<<<dim3(6, 4), 256, 0, stream>>>(hbar, Wlt, skp);
  k_red_agg<<<128, 256, 0, stream>>>(skp, bl, bt, out, cvec);
  k_skgemm<<<dim3(6, 4), 256, 0, stream>>>(out + O_AGGL, Wtb, skp);
  k_attnpool<<<dim3(32, 16), 512, 0, stream>>>(hs, skp, cvec, lmask, amask, atemp, po, pml);
  k_finish<<<128, 192, 0, stream>>>(po, pml, hst);
  k_skgemm<<<dim3(6, 4), 256, 0, stream>>>(hst, Wtt, skp);
  k_head<<<128, 64, 0, stream>>>(skp, bt, lsc, out);
}

// Round 20
// 84.276 us; speedup vs baseline: 1.0162x; 1.0023x over previous
//
#include <hip/hip_runtime.h>
#include <hip/hip_bf16.h>

typedef __attribute__((ext_vector_type(8))) short s16x8;
typedef __attribute__((ext_vector_type(4))) short s16x4;
typedef __attribute__((ext_vector_type(4))) float f32x4;

#define BB 16
#define LL 2048
#define HH 768
#define DD 768
#define MM 8
#define NCH 16           // attnpool chunks (128 tokens each)

// d_out layout (float elements)
#define O_LOGITS 0
#define O_BID    128
#define O_LID    256
#define O_AGGL   384
#define O_SCALE  98688
#define O_AGGT   98689

// ws layout (bytes)
#define WTT_OFF  0u          // Wt^T bf16 768*768*2
#define WLT_OFF  1179648u    // Wl^T bf16
#define WTB_OFF  2359296u    // Wt bf16 (natural)
#define HBAR_OFF 3538944u    // 128*768 fp32
#define HST_OFF  4325376u    // 128*768 fp32
#define CVEC_OFF 4718592u    // 128 fp32
#define PML_OFF  4719104u    // 16*16*8*2 fp32 = 16384
#define PO_OFF   4751872u    // 16*16*8*768 bf16 = 3145728
#define SK_OFF   17334784u   // 4*128*768 fp32 (split-K partials, reused)

__device__ __forceinline__ short f2bf(float x) {
  union { float f; unsigned u; } v; v.f = x;
  unsigned r = v.u + 0x7FFFu + ((v.u >> 16) & 1u);
  return (short)(r >> 16);
}
__device__ __forceinline__ float bf2f(short x) {
  union { unsigned u; float f; } v; v.u = ((unsigned)(unsigned short)x) << 16;
  return v.f;
}

// async global->LDS, 16B per lane; LDS dest is wave-uniform base (HW adds lane*16)
#define GLOAD_LDS16(gp, lp) __builtin_amdgcn_global_load_lds( \
    (const __attribute__((address_space(1))) unsigned int*)(gp), \
    (__attribute__((address_space(3))) unsigned int*)(lp), 16, 0, 0)

// ---------------------------------------------------------------- prep: W converts + hbar (fused)
__global__ void k_prep(const float* __restrict__ Wt, const float* __restrict__ Wl,
                       short* __restrict__ Wtt, short* __restrict__ Wlt,
                       short* __restrict__ Wtb,
                       const float* __restrict__ hs, const int* __restrict__ lmask,
                       float* __restrict__ hbar) {
  __shared__ float tile[64][65];
  __shared__ int list[LL];
  __shared__ int nlist_s;
  int bx = blockIdx.x;
  int t = threadIdx.x;
  if (bx < 432) {
    int z = bx / 144, r = bx % 144;
    int kb = (r % 12) * 64, nb = (r / 12) * 64;
    int c = t & 63;
    int r0 = (t >> 6) * 16;
    if (z == 2) {
#pragma unroll
      for (int i = 0; i < 16; ++i) {
        int rr = kb + r0 + i;
        Wtb[(size_t)rr * DD + nb + c] = f2bf(Wt[(size_t)rr * DD + nb + c]);
      }
      return;
    }
    const float* src = z ? Wl : Wt;
    short* dst = z ? Wlt : Wtt;
#pragma unroll
    for (int i = 0; i < 16; ++i)
      tile[r0 + i][c] = src[(size_t)(kb + r0 + i) * DD + nb + c];
    __syncthreads();
#pragma unroll
    for (int i = 0; i < 16; ++i)
      dst[(size_t)(nb + r0 + i) * HH + kb + c] = f2bf(tile[c][r0 + i]);
    return;
  }
  int bh = bx - 432;
  int b = bh >> 3, m = bh & 7;
  int lane = t & 63, w = t >> 6;
  if (w == 0) {                       // deterministic compaction
    int base = 0;
    for (int win = 0; win < LL / 64; ++win) {
      int l = win * 64 + lane;
      bool match = (lmask[b * LL + l] == m + 1);
      unsigned long long mk = __ballot(match);
      if (match) {
        int pos = base + (int)__popcll(mk & ((1ull << lane) - 1ull));
        list[pos] = l;
      }
      base += (int)__popcll(mk);
    }
    if (lane == 0) nlist_s = base;
  }
  __syncthreads();
  int n = nlist_s;
  float inv = 1.0f / (float)(n > 1 ? n : 1);
  float a0 = 0.f, a1 = 0.f, a2 = 0.f;
  for (int i = 0; i < n; ++i) {
    const float* rr = hs + (size_t)(b * LL + list[i]) * HH;
    a0 += rr[t]; a1 += rr[t + 256]; a2 += rr[t + 512];
  }
  float* dst = hbar + (size_t)(b * MM + m) * HH;
  dst[t] = a0 * inv; dst[t + 256] = a1 * inv; dst[t + 512] = a2 * inv;
}

// ---------------------------------------------------------------- split-K 128x768 GEMM (K=768/4)
// r13-proven LDS-staged body (issue-ahead queue = the latency hiding for
// 24-block grids; direct-fragment regressed — r14/r15 lesson).
__global__ __launch_bounds__(256, 3)
void k_skgemm(const float* __restrict__ A, const short* __restrict__ Bt,
              float* __restrict__ part) {
  __shared__ short As[128][64];
  __shared__ short Bs[2][128][64];
  int t = threadIdx.x;
  int lane = t & 63, w = t >> 6;
  int wm = w >> 1, wn = w & 1;
  int n0 = blockIdx.x * 128;
  int kt0 = blockIdx.y * 3;

  f32x4 acc[4][4] = {};
  float4 areg[8];

  auto issueA = [&](int kt) {
    const float* Ag = A + (size_t)(kt0 + kt) * 64;
#pragma unroll
    for (int i = 0; i < 8; ++i) {
      int slot = i * 256 + t;
      int row = slot >> 4, c = slot & 15;
      areg[i] = *(const float4*)(Ag + (size_t)row * HH + c * 4);
    }
  };
  auto issueB = [&](int kt, int buf) {
    const short* Bg = Bt + (size_t)n0 * HH + (size_t)(kt0 + kt) * 64;
#pragma unroll
    for (int i = 0; i < 4; ++i) {
      int slot = i * 256 + w * 64 + lane;
      int row = slot >> 3, c = slot & 7;
      int cs = c ^ (row & 7);
      GLOAD_LDS16(Bg + (size_t)row * HH + cs * 8,
                  (char*)&Bs[0][0][0] + (size_t)buf * 16384 + (size_t)(i * 256 + w * 64) * 16);
    }
  };
  auto writeA = [&]() {
#pragma unroll
    for (int i = 0; i < 8; ++i) {
      int slot = i * 256 + t;
      int row = slot >> 4, c = slot & 15;
      unsigned d0, d1;
      asm("v_cvt_pk_bf16_f32 %0, %1, %2" : "=v"(d0) : "v"(areg[i].x), "v"(areg[i].y));
      asm("v_cvt_pk_bf16_f32 %0, %1, %2" : "=v"(d1) : "v"(areg[i].z), "v"(areg[i].w));
      int phys = (c >> 1) ^ (row & 7);
      uint2 val = {d0, d1};
      *(uint2*)((char*)&As[0][0] + (size_t)row * 128 + phys * 16 + (c & 1) * 8) = val;
    }
  };
  auto compute = [&](int buf) {
#pragma unroll
    for (int kk = 0; kk < 2; ++kk) {
      s16x8 a[4], bb[4];
#pragma unroll
      for (int i = 0; i < 4; ++i) {
        int row = wm * 64 + i * 16 + (lane & 15);
        int p = (kk * 4 + (lane >> 4)) ^ (row & 7);
        a[i] = *(const s16x8*)((const char*)&As[0][0] + (size_t)row * 128 + p * 16);
      }
#pragma unroll
      for (int i = 0; i < 4; ++i) {
        int row = wn * 64 + i * 16 + (lane & 15);
        int p = (kk * 4 + (lane >> 4)) ^ (row & 7);
        bb[i] = *(const s16x8*)((const char*)&Bs[0][0][0] + (size_t)buf * 16384 + (size_t)row * 128 + p * 16);
      }
#pragma unroll
      for (int mi = 0; mi < 4; ++mi)
#pragma unroll
        for (int ni = 0; ni < 4; ++ni)
          acc[mi][ni] = __builtin_amdgcn_mfma_f32_16x16x32_bf16(a[mi], bb[ni], acc[mi][ni], 0, 0, 0);
    }
  };

  issueA(0); issueB(0, 0);
  writeA();
  __syncthreads();
  for (int kt = 0; kt < 3; ++kt) {
    if (kt + 1 < 3) { issueA(kt + 1); issueB(kt + 1, (kt + 1) & 1); }
    compute(kt & 1);
    __syncthreads();
    if (kt + 1 < 3) {
      writeA();
      __syncthreads();
    }
  }

  float* po = part + (size_t)blockIdx.y * 128 * HH;
#pragma unroll
  for (int mi = 0; mi < 4; ++mi) {
    int row = wm * 64 + mi * 16 + ((lane >> 4) * 4);
#pragma unroll
    for (int ni = 0; ni < 4; ++ni) {
      int col = n0 + wn * 64 + ni * 16 + (lane & 15);
#pragma unroll
      for (int j = 0; j < 4; ++j)
        po[(size_t)(row + j) * HH + col] = acc[mi][ni][j];
    }
  }
}

// ---------------------------------------------------------------- reduce partials -> agg (+bl), cvec
__global__ void k_red_agg(const float* __restrict__ part, const float* __restrict__ bl,
                          const float* __restrict__ bt, float* __restrict__ out,
                          float* __restrict__ cvec) {
  int row = blockIdx.x;
  int t = threadIdx.x;
  int lane = t & 63, w = t >> 6;
  __shared__ float wred[4];
  float dotbt = 0.f;
#pragma unroll
  for (int cc = 0; cc < 3; ++cc) {
    int c = cc * 256 + t;
    float s = bl[c];
#pragma unroll
    for (int kc = 0; kc < 4; ++kc)
      s += part[((size_t)kc * 128 + row) * HH + c];
    out[O_AGGL + (size_t)row * DD + c] = s;
    dotbt += s * bt[c];
  }
  for (int sh = 32; sh; sh >>= 1) dotbt += __shfl_xor(dotbt, sh, 64);
  if (lane == 0) wred[w] = dotbt;
  __syncthreads();
  if (t == 0) cvec[row] = wred[0] + wred[1] + wred[2] + wred[3];
}

// ---------------------------------------------------------------- fused scores+softmax-partial+pool
// 128-token chunks (16 chunks): halves po traffic, Bs-staging cost, and
// finish depth vs r19. Phase 1: split-K wave pairs, wave-private dbuf staging
// (barrier-free), run twice (two 64-token subtiles). po stored bf16.
__global__ __launch_bounds__(512)
void k_attnpool(const float* __restrict__ hs, const float* __restrict__ qhp,
                const float* __restrict__ cvec, const int* __restrict__ lmask,
                const int* __restrict__ amask, const float* __restrict__ temp_p,
                short* __restrict__ part_o, float* __restrict__ part_ml) {
  __shared__ short As[8][2][16][64];  // wave-private double buffers, 32 KB
  __shared__ short Bs[16][776];       // 24.8 KB (rows 8..15 zero)
  __shared__ float w_acc[4][64][4];   // 4 KB split-K combine
  __shared__ float w_lds[128][8];     // 4 KB
  int chunk = blockIdx.x;             // 16 chunks of 128 tokens
  int b = blockIdx.y;                 // 16
  int t = threadIdx.x;
  int lane = t & 63, w = t >> 6;      // w 0..7
  int wq = w & 3, kw = w >> 2;        // token quad, K-half

  // stage qh = sum of 4 split-K partials (L2-hot), bf16; rows 8..15 zero
  for (int c = t; c < HH; c += 512) {
#pragma unroll
    for (int r = 0; r < 8; ++r) {
      size_t o = (size_t)(b * MM + r) * HH + c;
      float s = qhp[o] + qhp[(size_t)128 * HH + o] + qhp[(size_t)256 * HH + o] + qhp[(size_t)384 * HH + o];
      Bs[r][c] = f2bf(s);
    }
#pragma unroll
    for (int r = 8; r < 16; ++r) Bs[r][c] = 0;
  }

  const float* Hg = hs + (size_t)(b * LL + chunk * 128) * HH;
  int kbase = kw * 384;                              // this wave's K-half
  float inv_temp = 1.0f / fmaxf(fabsf(temp_p[0]), 0.1f);
  float4 areg[2][4];
  __syncthreads();                     // Bs visible before first subtile MFMA

#pragma unroll
  for (int st = 0; st < 2; ++st) {
    const float* Wrow = Hg + (size_t)(st * 64 + wq * 16) * HH;  // wave's 16 rows

    auto issueA = [&](int set, int kt) {
#pragma unroll
      for (int i = 0; i < 4; ++i) {
        int slot = i * 64 + lane;
        int row = slot >> 4, c = slot & 15;
        if (set == 0)
          areg[0][i] = *(const float4*)(Wrow + (size_t)row * HH + kbase + kt * 64 + c * 4);
        else
          areg[1][i] = *(const float4*)(Wrow + (size_t)row * HH + kbase + kt * 64 + c * 4);
      }
    };
    auto writeA = [&](int set, int buf) {
#pragma unroll
      for (int i = 0; i < 4; ++i) {
        int slot = i * 64 + lane;
        int row = slot >> 4, c = slot & 15;
        float4 v = set == 0 ? areg[0][i] : areg[1][i];
        unsigned d0, d1;
        asm("v_cvt_pk_bf16_f32 %0, %1, %2" : "=v"(d0) : "v"(v.x), "v"(v.y));
        asm("v_cvt_pk_bf16_f32 %0, %1, %2" : "=v"(d1) : "v"(v.z), "v"(v.w));
        int phys = (c >> 1) ^ (row & 7);
        uint2 val = {d0, d1};
        *(uint2*)((char*)&As[w][buf][0][0] + (size_t)row * 128 + phys * 16 + (c & 1) * 8) = val;
      }
    };

    f32x4 acc = {};
    issueA(0, 0); issueA(1, 1);
    writeA(0, 0);
#pragma unroll
    for (int kt = 0; kt < 6; ++kt) {
      int buf = kt & 1;
#pragma unroll
      for (int kk = 0; kk < 2; ++kk) {
        int r = lane & 15;
        int p = (kk * 4 + (lane >> 4)) ^ (r & 7);
        s16x8 a = *(const s16x8*)((const char*)&As[w][buf][0][0] + (size_t)r * 128 + p * 16);
        s16x8 bfr = *(const s16x8*)&Bs[lane & 15][kbase + kt * 64 + kk * 32 + (lane >> 4) * 8];
        acc = __builtin_amdgcn_mfma_f32_16x16x32_bf16(a, bfr, acc, 0, 0, 0);
      }
      if (kt + 1 < 6) writeA((kt + 1) & 1, (kt + 1) & 1);
      if (kt + 2 < 6) issueA(kt & 1, kt + 2);
    }

    // combine K-halves: waves 4..7 deposit, waves 0..3 add
    if (kw == 1) {
      w_acc[wq][lane][0] = acc[0]; w_acc[wq][lane][1] = acc[1];
      w_acc[wq][lane][2] = acc[2]; w_acc[wq][lane][3] = acc[3];
    }
    __syncthreads();
    if (kw == 0) {
      acc[0] += w_acc[wq][lane][0]; acc[1] += w_acc[wq][lane][1];
      acc[2] += w_acc[wq][lane][2]; acc[3] += w_acc[wq][lane][3];
    }

    // epilogue (waves 0..3) -> s rows st*64.. in LDS
    int m = lane & 15;
    int tok0 = st * 64 + wq * 16 + (lane >> 4) * 4;
    if (kw == 0 && m < MM) {
      float cv = cvec[b * MM + m];
      int4 lm = *(const int4*)&lmask[b * LL + chunk * 128 + tok0];
      int4 am = *(const int4*)&amask[b * LL + chunk * 128 + tok0];
      w_lds[tok0 + 0][m] = (lm.x == 0 && am.x == 1) ? (acc[0] + cv) * inv_temp : -1e30f;
      w_lds[tok0 + 1][m] = (lm.y == 0 && am.y == 1) ? (acc[1] + cv) * inv_temp : -1e30f;
      w_lds[tok0 + 2][m] = (lm.z == 0 && am.z == 1) ? (acc[2] + cv) * inv_temp : -1e30f;
      w_lds[tok0 + 3][m] = (lm.w == 0 && am.w == 1) ? (acc[3] + cv) * inv_temp : -1e30f;
    }
    __syncthreads();                   // w_acc free for next subtile / w_lds done
  }

  // Phase 2: wave w handles m = w over 128 tokens (2 per lane)
  {
    float v0 = w_lds[lane][w], v1 = w_lds[64 + lane][w];
    float mx = fmaxf(v0, v1);
    for (int s = 32; s; s >>= 1) mx = fmaxf(mx, __shfl_xor(mx, s, 64));
    float e0 = __expf(v0 - mx), e1 = __expf(v1 - mx);
    float l = e0 + e1;
    for (int s = 32; s; s >>= 1) l += __shfl_xor(l, s, 64);
    w_lds[lane][w] = e0; w_lds[64 + lane][w] = e1;
    if (lane == 0) {
      float* pml = part_ml + ((size_t)(chunk * BB + b) * MM + w) * 2;
      pml[0] = mx; pml[1] = l;
    }
  }
  __syncthreads();

  // Phase 3: partial pool over 128 tokens; threads 0..383 own 2 h-cols (L3-hot)
  if (t < 384) {
    int h0 = t * 2;
    float2 o[8] = {};
    const float* hp = Hg + h0;
    for (int tok = 0; tok < 128; ++tok) {
      float2 hv = *(const float2*)(hp + (size_t)tok * HH);
      float4 w0 = *(const float4*)&w_lds[tok][0];
      float4 w1 = *(const float4*)&w_lds[tok][4];
      o[0].x += w0.x * hv.x; o[0].y += w0.x * hv.y;
      o[1].x += w0.y * hv.x; o[1].y += w0.y * hv.y;
      o[2].x += w0.z * hv.x; o[2].y += w0.z * hv.y;
      o[3].x += w0.w * hv.x; o[3].y += w0.w * hv.y;
      o[4].x += w1.x * hv.x; o[4].y += w1.x * hv.y;
      o[5].x += w1.y * hv.x; o[5].y += w1.y * hv.y;
      o[6].x += w1.z * hv.x; o[6].y += w1.z * hv.y;
      o[7].x += w1.w * hv.x; o[7].y += w1.w * hv.y;
    }
    short* po = part_o + (size_t)(chunk * BB + b) * MM * HH + h0;
#pragma unroll
    for (int mm = 0; mm < 8; ++mm) {
      short2 pv = {f2bf(o[mm].x), f2bf(o[mm].y)};
      *(short2*)(po + (size_t)mm * HH) = pv;
    }
  }
}

// ---------------------------------------------------------------- finish: flash-reduce partials -> hst
__global__ void k_finish(const short* __restrict__ part_o, const float* __restrict__ part_ml,
                         float* __restrict__ hst) {
  int row = blockIdx.x;
  int b = row >> 3, m = row & 7;
  int t = threadIdx.x;     // 192
  float mg = -1e30f;
#pragma unroll
  for (int lc = 0; lc < NCH; ++lc)
    mg = fmaxf(mg, part_ml[((size_t)(lc * BB + b) * MM + m) * 2]);
  float L = 0.f;
  f32x4 acc = {};
  int h0 = t * 4;
  for (int lc = 0; lc < NCH; ++lc) {
    const float* pml = part_ml + ((size_t)(lc * BB + b) * MM + m) * 2;
    float f = __expf(pml[0] - mg);
    L += pml[1] * f;
    s16x4 v = *(const s16x4*)(part_o + ((size_t)(lc * BB + b) * MM + m) * HH + h0);
    acc[0] += bf2f(v[0]) * f; acc[1] += bf2f(v[1]) * f;
    acc[2] += bf2f(v[2]) * f; acc[3] += bf2f(v[3]) * f;
  }
  float inv = 1.0f / L;
  f32x4 r = {acc[0] * inv, acc[1] * inv, acc[2] * inv, acc[3] * inv};
  *(f32x4*)(hst + (size_t)row * HH + h0) = r;
}

// ---------------------------------------------------------------- head: aggt reduce + write + cosine
__global__ void k_head(const float* __restrict__ part, const float* __restrict__ bt,
                       const float* __restrict__ lscale_p, float* __restrict__ out) {
  int row = blockIdx.x;   // 128
  int lane = threadIdx.x; // 64
  const float* al = out + O_AGGL + (size_t)row * DD;
  float dot = 0.f, nt = 0.f, nl = 0.f;
  for (int i = lane; i < DD; i += 64) {
    float a = bt[i];
#pragma unroll
    for (int kc = 0; kc < 4; ++kc)
      a += part[((size_t)kc * 128 + row) * HH + i];
    out[O_AGGT + (size_t)row * DD + i] = a;
    float c = al[i];
    dot += a * c; nt += a * a; nl += c * c;
  }
  for (int s = 32; s; s >>= 1) {
    dot += __shfl_xor(dot, s, 64);
    nt  += __shfl_xor(nt, s, 64);
    nl  += __shfl_xor(nl, s, 64);
  }
  if (lane == 0) {
    float scale = expf(lscale_p[0]);
    float denom = fmaxf(sqrtf(nt), 1e-8f) * fmaxf(sqrtf(nl), 1e-8f);
    out[O_LOGITS + row] = dot / denom * scale;
    out[O_BID + row] = (float)(row >> 3);
    out[O_LID + row] = (float)((row & 7) + 1);
    if (row == 0) out[O_SCALE] = scale;
  }
}

extern "C" void kernel_launch(void* const* d_in, const int* in_sizes, int n_in,
                              void* d_out, int out_size, void* d_ws, size_t ws_size,
                              hipStream_t stream) {
  const float* hs    = (const float*)d_in[0];
  const float* Wt    = (const float*)d_in[1];
  const float* bt    = (const float*)d_in[2];
  const float* Wl    = (const float*)d_in[3];
  const float* bl    = (const float*)d_in[4];
  const float* atemp = (const float*)d_in[5];
  const float* lsc   = (const float*)d_in[6];
  const int*   lmask = (const int*)d_in[7];
  const int*   amask = (const int*)d_in[9];
  float* out = (float*)d_out;
  char* ws = (char*)d_ws;
  short* Wtt  = (short*)(ws + WTT_OFF);
  short* Wlt  = (short*)(ws + WLT_OFF);
  short* Wtb  = (short*)(ws + WTB_OFF);
  float* hbar = (float*)(ws + HBAR_OFF);
  float* hst  = (float*)(ws + HST_OFF);
  float* cvec = (float*)(ws + CVEC_OFF);
  float* pml  = (float*)(ws + PML_OFF);
  short* po   = (short*)(ws + PO_OFF);
  float* skp  = (float*)(ws + SK_OFF);

  k_prep<<<560, 256, 0, stream>>>(Wt, Wl, Wtt, Wlt, Wtb, hs, lmask, hbar);
  k_skgemm<<<dim3(6, 4), 256, 0, stream>>>(hbar, Wlt, skp);
  k_red_agg<<<128, 256, 0, stream>>>(skp, bl, bt, out, cvec);
  k_skgemm<<<dim3(6, 4), 256, 0, stream>>>(out + O_AGGL, Wtb, skp);
  k_attnpool<<<dim3(NCH, 16), 512, 0, stream>>>(hs, skp, cvec, lmask, amask, atemp, po, pml);
  k_finish<<<128, 192, 0, stream>>>(po, pml, hst);
  k_skgemm<<<dim3(6, 4), 256, 0, stream>>>(hst, Wtt, skp);
  k_head<<<128, 64, 0, stream>>>(skp, bt, lsc, out);
}

// Round 21
// 83.503 us; speedup vs baseline: 1.0256x; 1.0093x over previous
//
#include <hip/hip_runtime.h>
#include <hip/hip_bf16.h>

typedef __attribute__((ext_vector_type(8))) short s16x8;
typedef __attribute__((ext_vector_type(4))) short s16x4;
typedef __attribute__((ext_vector_type(4))) float f32x4;

#define BB 16
#define LL 2048
#define HH 768
#define DD 768
#define MM 8
#define NCH 32           // attnpool chunks (64 tokens each; 512 blocks = 2/CU)

// d_out layout (float elements)
#define O_LOGITS 0
#define O_BID    128
#define O_LID    256
#define O_AGGL   384
#define O_SCALE  98688
#define O_AGGT   98689

// ws layout (bytes)
#define WTT_OFF  0u          // Wt^T bf16 768*768*2
#define WLT_OFF  1179648u    // Wl^T bf16
#define WTB_OFF  2359296u    // Wt bf16 (natural)
#define HBAR_OFF 3538944u    // 128*768 fp32
#define HST_OFF  4325376u    // 128*768 fp32
#define CVEC_OFF 4718592u    // 128 fp32
#define PML_OFF  4719104u    // 32*16*8*2 fp32 = 32768
#define PO_OFF   4751872u    // 32*16*8*768 bf16 = 6291456
#define SK_OFF   17334784u   // 4*128*768 fp32 (split-K partials, reused)

__device__ __forceinline__ short f2bf(float x) {
  union { float f; unsigned u; } v; v.f = x;
  unsigned r = v.u + 0x7FFFu + ((v.u >> 16) & 1u);
  return (short)(r >> 16);
}
__device__ __forceinline__ float bf2f(short x) {
  union { unsigned u; float f; } v; v.u = ((unsigned)(unsigned short)x) << 16;
  return v.f;
}

// async global->LDS, 16B per lane; LDS dest is wave-uniform base (HW adds lane*16)
#define GLOAD_LDS16(gp, lp) __builtin_amdgcn_global_load_lds( \
    (const __attribute__((address_space(1))) unsigned int*)(gp), \
    (__attribute__((address_space(3))) unsigned int*)(lp), 16, 0, 0)

// ---------------------------------------------------------------- prep: W converts + hbar (fused)
__global__ void k_prep(const float* __restrict__ Wt, const float* __restrict__ Wl,
                       short* __restrict__ Wtt, short* __restrict__ Wlt,
                       short* __restrict__ Wtb,
                       const float* __restrict__ hs, const int* __restrict__ lmask,
                       float* __restrict__ hbar) {
  __shared__ float tile[64][65];
  __shared__ int list[LL];
  __shared__ int nlist_s;
  int bx = blockIdx.x;
  int t = threadIdx.x;
  if (bx < 432) {
    int z = bx / 144, r = bx % 144;
    int kb = (r % 12) * 64, nb = (r / 12) * 64;
    int c = t & 63;
    int r0 = (t >> 6) * 16;
    if (z == 2) {
#pragma unroll
      for (int i = 0; i < 16; ++i) {
        int rr = kb + r0 + i;
        Wtb[(size_t)rr * DD + nb + c] = f2bf(Wt[(size_t)rr * DD + nb + c]);
      }
      return;
    }
    const float* src = z ? Wl : Wt;
    short* dst = z ? Wlt : Wtt;
#pragma unroll
    for (int i = 0; i < 16; ++i)
      tile[r0 + i][c] = src[(size_t)(kb + r0 + i) * DD + nb + c];
    __syncthreads();
#pragma unroll
    for (int i = 0; i < 16; ++i)
      dst[(size_t)(nb + r0 + i) * HH + kb + c] = f2bf(tile[c][r0 + i]);
    return;
  }
  int bh = bx - 432;
  int b = bh >> 3, m = bh & 7;
  int lane = t & 63, w = t >> 6;
  if (w == 0) {                       // deterministic compaction
    int base = 0;
    for (int win = 0; win < LL / 64; ++win) {
      int l = win * 64 + lane;
      bool match = (lmask[b * LL + l] == m + 1);
      unsigned long long mk = __ballot(match);
      if (match) {
        int pos = base + (int)__popcll(mk & ((1ull << lane) - 1ull));
        list[pos] = l;
      }
      base += (int)__popcll(mk);
    }
    if (lane == 0) nlist_s = base;
  }
  __syncthreads();
  int n = nlist_s;
  float inv = 1.0f / (float)(n > 1 ? n : 1);
  float a0 = 0.f, a1 = 0.f, a2 = 0.f;
  for (int i = 0; i < n; ++i) {
    const float* rr = hs + (size_t)(b * LL + list[i]) * HH;
    a0 += rr[t]; a1 += rr[t + 256]; a2 += rr[t + 512];
  }
  float* dst = hbar + (size_t)(b * MM + m) * HH;
  dst[t] = a0 * inv; dst[t + 256] = a1 * inv; dst[t + 512] = a2 * inv;
}

// ---------------------------------------------------------------- split-K 128x768 GEMM (K=768/4)
// r13-proven LDS-staged body (issue-ahead queue = the latency hiding for
// 24-block grids; direct-fragment regressed — r14/r15 lesson).
__global__ __launch_bounds__(256, 3)
void k_skgemm(const float* __restrict__ A, const short* __restrict__ Bt,
              float* __restrict__ part) {
  __shared__ short As[128][64];
  __shared__ short Bs[2][128][64];
  int t = threadIdx.x;
  int lane = t & 63, w = t >> 6;
  int wm = w >> 1, wn = w & 1;
  int n0 = blockIdx.x * 128;
  int kt0 = blockIdx.y * 3;

  f32x4 acc[4][4] = {};
  float4 areg[8];

  auto issueA = [&](int kt) {
    const float* Ag = A + (size_t)(kt0 + kt) * 64;
#pragma unroll
    for (int i = 0; i < 8; ++i) {
      int slot = i * 256 + t;
      int row = slot >> 4, c = slot & 15;
      areg[i] = *(const float4*)(Ag + (size_t)row * HH + c * 4);
    }
  };
  auto issueB = [&](int kt, int buf) {
    const short* Bg = Bt + (size_t)n0 * HH + (size_t)(kt0 + kt) * 64;
#pragma unroll
    for (int i = 0; i < 4; ++i) {
      int slot = i * 256 + w * 64 + lane;
      int row = slot >> 3, c = slot & 7;
      int cs = c ^ (row & 7);
      GLOAD_LDS16(Bg + (size_t)row * HH + cs * 8,
                  (char*)&Bs[0][0][0] + (size_t)buf * 16384 + (size_t)(i * 256 + w * 64) * 16);
    }
  };
  auto writeA = [&]() {
#pragma unroll
    for (int i = 0; i < 8; ++i) {
      int slot = i * 256 + t;
      int row = slot >> 4, c = slot & 15;
      unsigned d0, d1;
      asm("v_cvt_pk_bf16_f32 %0, %1, %2" : "=v"(d0) : "v"(areg[i].x), "v"(areg[i].y));
      asm("v_cvt_pk_bf16_f32 %0, %1, %2" : "=v"(d1) : "v"(areg[i].z), "v"(areg[i].w));
      int phys = (c >> 1) ^ (row & 7);
      uint2 val = {d0, d1};
      *(uint2*)((char*)&As[0][0] + (size_t)row * 128 + phys * 16 + (c & 1) * 8) = val;
    }
  };
  auto compute = [&](int buf) {
#pragma unroll
    for (int kk = 0; kk < 2; ++kk) {
      s16x8 a[4], bb[4];
#pragma unroll
      for (int i = 0; i < 4; ++i) {
        int row = wm * 64 + i * 16 + (lane & 15);
        int p = (kk * 4 + (lane >> 4)) ^ (row & 7);
        a[i] = *(const s16x8*)((const char*)&As[0][0] + (size_t)row * 128 + p * 16);
      }
#pragma unroll
      for (int i = 0; i < 4; ++i) {
        int row = wn * 64 + i * 16 + (lane & 15);
        int p = (kk * 4 + (lane >> 4)) ^ (row & 7);
        bb[i] = *(const s16x8*)((const char*)&Bs[0][0][0] + (size_t)buf * 16384 + (size_t)row * 128 + p * 16);
      }
#pragma unroll
      for (int mi = 0; mi < 4; ++mi)
#pragma unroll
        for (int ni = 0; ni < 4; ++ni)
          acc[mi][ni] = __builtin_amdgcn_mfma_f32_16x16x32_bf16(a[mi], bb[ni], acc[mi][ni], 0, 0, 0);
    }
  };

  issueA(0); issueB(0, 0);
  writeA();
  __syncthreads();
  for (int kt = 0; kt < 3; ++kt) {
    if (kt + 1 < 3) { issueA(kt + 1); issueB(kt + 1, (kt + 1) & 1); }
    compute(kt & 1);
    __syncthreads();
    if (kt + 1 < 3) {
      writeA();
      __syncthreads();
    }
  }

  float* po = part + (size_t)blockIdx.y * 128 * HH;
#pragma unroll
  for (int mi = 0; mi < 4; ++mi) {
    int row = wm * 64 + mi * 16 + ((lane >> 4) * 4);
#pragma unroll
    for (int ni = 0; ni < 4; ++ni) {
      int col = n0 + wn * 64 + ni * 16 + (lane & 15);
#pragma unroll
      for (int j = 0; j < 4; ++j)
        po[(size_t)(row + j) * HH + col] = acc[mi][ni][j];
    }
  }
}

// ---------------------------------------------------------------- reduce partials -> agg (+bl), cvec
__global__ void k_red_agg(const float* __restrict__ part, const float* __restrict__ bl,
                          const float* __restrict__ bt, float* __restrict__ out,
                          float* __restrict__ cvec) {
  int row = blockIdx.x;
  int t = threadIdx.x;
  int lane = t & 63, w = t >> 6;
  __shared__ float wred[4];
  float dotbt = 0.f;
#pragma unroll
  for (int cc = 0; cc < 3; ++cc) {
    int c = cc * 256 + t;
    float s = bl[c];
#pragma unroll
    for (int kc = 0; kc < 4; ++kc)
      s += part[((size_t)kc * 128 + row) * HH + c];
    out[O_AGGL + (size_t)row * DD + c] = s;
    dotbt += s * bt[c];
  }
  for (int sh = 32; sh; sh >>= 1) dotbt += __shfl_xor(dotbt, sh, 64);
  if (lane == 0) wred[w] = dotbt;
  __syncthreads();
  if (t == 0) cvec[row] = wred[0] + wred[1] + wred[2] + wred[3];
}

// ---------------------------------------------------------------- fused scores+softmax-partial+pool
// r19 grid shape (64-token chunks, 512 blocks = 2/CU = 16 waves/CU — the
// occupancy that matters; r20's 128-chunks dropped to 1 block/CU and regressed)
// + r20's bf16 po traffic cut + unrolled phase-3 loads.
__global__ __launch_bounds__(512, 4)
void k_attnpool(const float* __restrict__ hs, const float* __restrict__ qhp,
                const float* __restrict__ cvec, const int* __restrict__ lmask,
                const int* __restrict__ amask, const float* __restrict__ temp_p,
                short* __restrict__ part_o, float* __restrict__ part_ml) {
  __shared__ short As[8][2][16][64];  // wave-private double buffers, 32 KB
  __shared__ short Bs[16][776];       // 24.8 KB (rows 8..15 zero)
  __shared__ float w_acc[4][64][4];   // 4 KB split-K combine
  __shared__ float w_lds[64][8];      // 2 KB
  int chunk = blockIdx.x;             // 32
  int b = blockIdx.y;                 // 16
  int t = threadIdx.x;
  int lane = t & 63, w = t >> 6;      // w 0..7
  int wq = w & 3, kw = w >> 2;        // token quad, K-half

  // stage qh = sum of 4 split-K partials (L2-hot), bf16; rows 8..15 zero
  for (int c = t; c < HH; c += 512) {
#pragma unroll
    for (int r = 0; r < 8; ++r) {
      size_t o = (size_t)(b * MM + r) * HH + c;
      float s = qhp[o] + qhp[(size_t)128 * HH + o] + qhp[(size_t)256 * HH + o] + qhp[(size_t)384 * HH + o];
      Bs[r][c] = f2bf(s);
    }
#pragma unroll
    for (int r = 8; r < 16; ++r) Bs[r][c] = 0;
  }

  const float* Hg = hs + (size_t)(b * LL + chunk * 64) * HH;
  const float* Wrow = Hg + (size_t)(wq * 16) * HH;   // this wave's 16 token rows
  int kbase = kw * 384;                              // this wave's K-half
  float4 areg[2][4];

  auto issueA = [&](int set, int kt) {
#pragma unroll
    for (int i = 0; i < 4; ++i) {
      int slot = i * 64 + lane;
      int row = slot >> 4, c = slot & 15;
      if (set == 0)
        areg[0][i] = *(const float4*)(Wrow + (size_t)row * HH + kbase + kt * 64 + c * 4);
      else
        areg[1][i] = *(const float4*)(Wrow + (size_t)row * HH + kbase + kt * 64 + c * 4);
    }
  };
  auto writeA = [&](int set, int buf) {
#pragma unroll
    for (int i = 0; i < 4; ++i) {
      int slot = i * 64 + lane;
      int row = slot >> 4, c = slot & 15;
      float4 v = set == 0 ? areg[0][i] : areg[1][i];
      unsigned d0, d1;
      asm("v_cvt_pk_bf16_f32 %0, %1, %2" : "=v"(d0) : "v"(v.x), "v"(v.y));
      asm("v_cvt_pk_bf16_f32 %0, %1, %2" : "=v"(d1) : "v"(v.z), "v"(v.w));
      int phys = (c >> 1) ^ (row & 7);
      uint2 val = {d0, d1};
      *(uint2*)((char*)&As[w][buf][0][0] + (size_t)row * 128 + phys * 16 + (c & 1) * 8) = val;
    }
  };

  f32x4 acc = {};
  issueA(0, 0); issueA(1, 1);
  writeA(0, 0);
  __syncthreads();                     // Bs visible (As slices wave-private)
#pragma unroll
  for (int kt = 0; kt < 6; ++kt) {
    int buf = kt & 1;
#pragma unroll
    for (int kk = 0; kk < 2; ++kk) {
      int r = lane & 15;
      int p = (kk * 4 + (lane >> 4)) ^ (r & 7);
      s16x8 a = *(const s16x8*)((const char*)&As[w][buf][0][0] + (size_t)r * 128 + p * 16);
      s16x8 bfr = *(const s16x8*)&Bs[lane & 15][kbase + kt * 64 + kk * 32 + (lane >> 4) * 8];
      acc = __builtin_amdgcn_mfma_f32_16x16x32_bf16(a, bfr, acc, 0, 0, 0);
    }
    if (kt + 1 < 6) writeA((kt + 1) & 1, (kt + 1) & 1);
    if (kt + 2 < 6) issueA(kt & 1, kt + 2);
  }

  // combine K-halves: waves 4..7 deposit, waves 0..3 add
  if (kw == 1) {
    w_acc[wq][lane][0] = acc[0]; w_acc[wq][lane][1] = acc[1];
    w_acc[wq][lane][2] = acc[2]; w_acc[wq][lane][3] = acc[3];
  }
  __syncthreads();
  if (kw == 0) {
    acc[0] += w_acc[wq][lane][0]; acc[1] += w_acc[wq][lane][1];
    acc[2] += w_acc[wq][lane][2]; acc[3] += w_acc[wq][lane][3];
  }

  // epilogue (waves 0..3) -> s in LDS
  float inv_temp = 1.0f / fmaxf(fabsf(temp_p[0]), 0.1f);
  int m = lane & 15;
  int tok0 = wq * 16 + (lane >> 4) * 4;
  if (kw == 0 && m < MM) {
    float cv = cvec[b * MM + m];
    int4 lm = *(const int4*)&lmask[b * LL + chunk * 64 + tok0];
    int4 am = *(const int4*)&amask[b * LL + chunk * 64 + tok0];
    w_lds[tok0 + 0][m] = (lm.x == 0 && am.x == 1) ? (acc[0] + cv) * inv_temp : -1e30f;
    w_lds[tok0 + 1][m] = (lm.y == 0 && am.y == 1) ? (acc[1] + cv) * inv_temp : -1e30f;
    w_lds[tok0 + 2][m] = (lm.z == 0 && am.z == 1) ? (acc[2] + cv) * inv_temp : -1e30f;
    w_lds[tok0 + 3][m] = (lm.w == 0 && am.w == 1) ? (acc[3] + cv) * inv_temp : -1e30f;
  }
  __syncthreads();

  // Phase 2: wave w handles m = w (one token per lane, single pass)
  {
    float v = w_lds[lane][w];
    float mx = v;
    for (int s = 32; s; s >>= 1) mx = fmaxf(mx, __shfl_xor(mx, s, 64));
    float e = __expf(v - mx);
    float l = e;
    for (int s = 32; s; s >>= 1) l += __shfl_xor(l, s, 64);
    w_lds[lane][w] = e;
    if (lane == 0) {
      float* pml = part_ml + ((size_t)(chunk * BB + b) * MM + w) * 2;
      pml[0] = mx; pml[1] = l;
    }
  }
  __syncthreads();

  // Phase 3: partial pool; threads 0..383 own 2 h-cols each (unrolled for
  // L3-latency hiding); bf16 output halves the po round-trip.
  if (t < 384) {
    int h0 = t * 2;
    float2 o[8] = {};
    const float* hp = Hg + h0;
#pragma unroll 4
    for (int tok = 0; tok < 64; ++tok) {
      float2 hv = *(const float2*)(hp + (size_t)tok * HH);
      float4 w0 = *(const float4*)&w_lds[tok][0];
      float4 w1 = *(const float4*)&w_lds[tok][4];
      o[0].x += w0.x * hv.x; o[0].y += w0.x * hv.y;
      o[1].x += w0.y * hv.x; o[1].y += w0.y * hv.y;
      o[2].x += w0.z * hv.x; o[2].y += w0.z * hv.y;
      o[3].x += w0.w * hv.x; o[3].y += w0.w * hv.y;
      o[4].x += w1.x * hv.x; o[4].y += w1.x * hv.y;
      o[5].x += w1.y * hv.x; o[5].y += w1.y * hv.y;
      o[6].x += w1.z * hv.x; o[6].y += w1.z * hv.y;
      o[7].x += w1.w * hv.x; o[7].y += w1.w * hv.y;
    }
    short* po = part_o + (size_t)(chunk * BB + b) * MM * HH + h0;
#pragma unroll
    for (int mm = 0; mm < 8; ++mm) {
      short2 pv = {f2bf(o[mm].x), f2bf(o[mm].y)};
      *(short2*)(po + (size_t)mm * HH) = pv;
    }
  }
}

// ---------------------------------------------------------------- finish: flash-reduce partials -> hst
__global__ void k_finish(const short* __restrict__ part_o, const float* __restrict__ part_ml,
                         float* __restrict__ hst) {
  int row = blockIdx.x;
  int b = row >> 3, m = row & 7;
  int t = threadIdx.x;     // 192
  float mg = -1e30f;
#pragma unroll
  for (int lc = 0; lc < NCH; ++lc)
    mg = fmaxf(mg, part_ml[((size_t)(lc * BB + b) * MM + m) * 2]);
  float L = 0.f;
  f32x4 acc = {};
  int h0 = t * 4;
#pragma unroll 4
  for (int lc = 0; lc < NCH; ++lc) {
    const float* pml = part_ml + ((size_t)(lc * BB + b) * MM + m) * 2;
    float f = __expf(pml[0] - mg);
    L += pml[1] * f;
    s16x4 v = *(const s16x4*)(part_o + ((size_t)(lc * BB + b) * MM + m) * HH + h0);
    acc[0] += bf2f(v[0]) * f; acc[1] += bf2f(v[1]) * f;
    acc[2] += bf2f(v[2]) * f; acc[3] += bf2f(v[3]) * f;
  }
  float inv = 1.0f / L;
  f32x4 r = {acc[0] * inv, acc[1] * inv, acc[2] * inv, acc[3] * inv};
  *(f32x4*)(hst + (size_t)row * HH + h0) = r;
}

// ---------------------------------------------------------------- head: aggt reduce + write + cosine
__global__ void k_head(const float* __restrict__ part, const float* __restrict__ bt,
                       const float* __restrict__ lscale_p, float* __restrict__ out) {
  int row = blockIdx.x;   // 128
  int lane = threadIdx.x; // 64
  const float* al = out + O_AGGL + (size_t)row * DD;
  float dot = 0.f, nt = 0.f, nl = 0.f;
  for (int i = lane; i < DD; i += 64) {
    float a = bt[i];
#pragma unroll
    for (int kc = 0; kc < 4; ++kc)
      a += part[((size_t)kc * 128 + row) * HH + i];
    out[O_AGGT + (size_t)row * DD + i] = a;
    float c = al[i];
    dot += a * c; nt += a * a; nl += c * c;
  }
  for (int s = 32; s; s >>= 1) {
    dot += __shfl_xor(dot, s, 64);
    nt  += __shfl_xor(nt, s, 64);
    nl  += __shfl_xor(nl, s, 64);
  }
  if (lane == 0) {
    float scale = expf(lscale_p[0]);
    float denom = fmaxf(sqrtf(nt), 1e-8f) * fmaxf(sqrtf(nl), 1e-8f);
    out[O_LOGITS + row] = dot / denom * scale;
    out[O_BID + row] = (float)(row >> 3);
    out[O_LID + row] = (float)((row & 7) + 1);
    if (row == 0) out[O_SCALE] = scale;
  }
}

extern "C" void kernel_launch(void* const* d_in, const int* in_sizes, int n_in,
                              void* d_out, int out_size, void* d_ws, size_t ws_size,
                              hipStream_t stream) {
  const float* hs    = (const float*)d_in[0];
  const float* Wt    = (const float*)d_in[1];
  const float* bt    = (const float*)d_in[2];
  const float* Wl    = (const float*)d_in[3];
  const float* bl    = (const float*)d_in[4];
  const float* atemp = (const float*)d_in[5];
  const float* lsc   = (const float*)d_in[6];
  const int*   lmask = (const int*)d_in[7];
  const int*   amask = (const int*)d_in[9];
  float* out = (float*)d_out;
  char* ws = (char*)d_ws;
  short* Wtt  = (short*)(ws + WTT_OFF);
  short* Wlt  = (short*)(ws + WLT_OFF);
  short* Wtb  = (short*)(ws + WTB_OFF);
  float* hbar = (float*)(ws + HBAR_OFF);
  float* hst  = (float*)(ws + HST_OFF);
  float* cvec = (float*)(ws + CVEC_OFF);
  float* pml  = (float*)(ws + PML_OFF);
  short* po   = (short*)(ws + PO_OFF);
  float* skp  = (float*)(ws + SK_OFF);

  k_prep<<<560, 256, 0, stream>>>(Wt, Wl, Wtt, Wlt, Wtb, hs, lmask, hbar);
  k_skgemm<<<dim3(6, 4), 256, 0, stream>>>(hbar, Wlt, skp);
  k_red_agg<<<128, 256, 0, stream>>>(skp, bl, bt, out, cvec);
  k_skgemm<<<dim3(6, 4), 256, 0, stream>>>(out + O_AGGL, Wtb, skp);
  k_attnpool<<<dim3(NCH, 16), 512, 0, stream>>>(hs, skp, cvec, lmask, amask, atemp, po, pml);
  k_finish<<<128, 192, 0, stream>>>(po, pml, hst);
  k_skgemm<<<dim3(6, 4), 256, 0, stream>>>(hst, Wtt, skp);
  k_head<<<128, 64, 0, stream>>>(skp, bt, lsc, out);
}

// Round 22
// 83.486 us; speedup vs baseline: 1.0258x; 1.0002x over previous
//
#include <hip/hip_runtime.h>
#include <hip/hip_bf16.h>

typedef __attribute__((ext_vector_type(8))) short s16x8;
typedef __attribute__((ext_vector_type(4))) short s16x4;
typedef __attribute__((ext_vector_type(4))) float f32x4;

#define BB 16
#define LL 2048
#define HH 768
#define DD 768
#define MM 8
#define NCH 32           // attnpool chunks (64 tokens each; 512 blocks)

// d_out layout (float elements)
#define O_LOGITS 0
#define O_BID    128
#define O_LID    256
#define O_AGGL   384
#define O_SCALE  98688
#define O_AGGT   98689

// ws layout (bytes)
#define WTT_OFF  0u          // Wt^T bf16 768*768*2
#define WLT_OFF  1179648u    // Wl^T bf16
#define WTB_OFF  2359296u    // Wt bf16 (natural)
#define HBAR_OFF 3538944u    // 128*768 fp32
#define HST_OFF  4325376u    // 128*768 fp32
#define CVEC_OFF 4718592u    // 128 fp32
#define PML_OFF  4719104u    // 32*16*8*2 fp32 = 32768
#define PO_OFF   4751872u    // 32*16*8*768 bf16 = 6291456
#define SK_OFF   17334784u   // 4*128*768 fp32 (split-K partials, reused)

__device__ __forceinline__ short f2bf(float x) {
  union { float f; unsigned u; } v; v.f = x;
  unsigned r = v.u + 0x7FFFu + ((v.u >> 16) & 1u);
  return (short)(r >> 16);
}
__device__ __forceinline__ float bf2f(short x) {
  union { unsigned u; float f; } v; v.u = ((unsigned)(unsigned short)x) << 16;
  return v.f;
}

// async global->LDS, 16B per lane; LDS dest is wave-uniform base (HW adds lane*16)
#define GLOAD_LDS16(gp, lp) __builtin_amdgcn_global_load_lds( \
    (const __attribute__((address_space(1))) unsigned int*)(gp), \
    (__attribute__((address_space(3))) unsigned int*)(lp), 16, 0, 0)

// ---------------------------------------------------------------- prep: W converts + hbar (fused)
__global__ void k_prep(const float* __restrict__ Wt, const float* __restrict__ Wl,
                       short* __restrict__ Wtt, short* __restrict__ Wlt,
                       short* __restrict__ Wtb,
                       const float* __restrict__ hs, const int* __restrict__ lmask,
                       float* __restrict__ hbar) {
  __shared__ float tile[64][65];
  __shared__ int list[LL];
  __shared__ int nlist_s;
  int bx = blockIdx.x;
  int t = threadIdx.x;
  if (bx < 432) {
    int z = bx / 144, r = bx % 144;
    int kb = (r % 12) * 64, nb = (r / 12) * 64;
    int c = t & 63;
    int r0 = (t >> 6) * 16;
    if (z == 2) {
#pragma unroll
      for (int i = 0; i < 16; ++i) {
        int rr = kb + r0 + i;
        Wtb[(size_t)rr * DD + nb + c] = f2bf(Wt[(size_t)rr * DD + nb + c]);
      }
      return;
    }
    const float* src = z ? Wl : Wt;
    short* dst = z ? Wlt : Wtt;
#pragma unroll
    for (int i = 0; i < 16; ++i)
      tile[r0 + i][c] = src[(size_t)(kb + r0 + i) * DD + nb + c];
    __syncthreads();
#pragma unroll
    for (int i = 0; i < 16; ++i)
      dst[(size_t)(nb + r0 + i) * HH + kb + c] = f2bf(tile[c][r0 + i]);
    return;
  }
  int bh = bx - 432;
  int b = bh >> 3, m = bh & 7;
  int lane = t & 63, w = t >> 6;
  if (w == 0) {                       // deterministic compaction
    int base = 0;
    for (int win = 0; win < LL / 64; ++win) {
      int l = win * 64 + lane;
      bool match = (lmask[b * LL + l] == m + 1);
      unsigned long long mk = __ballot(match);
      if (match) {
        int pos = base + (int)__popcll(mk & ((1ull << lane) - 1ull));
        list[pos] = l;
      }
      base += (int)__popcll(mk);
    }
    if (lane == 0) nlist_s = base;
  }
  __syncthreads();
  int n = nlist_s;
  float inv = 1.0f / (float)(n > 1 ? n : 1);
  float a0 = 0.f, a1 = 0.f, a2 = 0.f;
  for (int i = 0; i < n; ++i) {
    const float* rr = hs + (size_t)(b * LL + list[i]) * HH;
    a0 += rr[t]; a1 += rr[t + 256]; a2 += rr[t + 512];
  }
  float* dst = hbar + (size_t)(b * MM + m) * HH;
  dst[t] = a0 * inv; dst[t + 256] = a1 * inv; dst[t + 512] = a2 * inv;
}

// ---------------------------------------------------------------- split-K 128x768 GEMM (K=768/4)
// r13-proven LDS-staged body (issue-ahead queue = the latency hiding for
// 24-block grids; direct-fragment regressed — r14/r15 lesson).
__global__ __launch_bounds__(256, 3)
void k_skgemm(const float* __restrict__ A, const short* __restrict__ Bt,
              float* __restrict__ part) {
  __shared__ short As[128][64];
  __shared__ short Bs[2][128][64];
  int t = threadIdx.x;
  int lane = t & 63, w = t >> 6;
  int wm = w >> 1, wn = w & 1;
  int n0 = blockIdx.x * 128;
  int kt0 = blockIdx.y * 3;

  f32x4 acc[4][4] = {};
  float4 areg[8];

  auto issueA = [&](int kt) {
    const float* Ag = A + (size_t)(kt0 + kt) * 64;
#pragma unroll
    for (int i = 0; i < 8; ++i) {
      int slot = i * 256 + t;
      int row = slot >> 4, c = slot & 15;
      areg[i] = *(const float4*)(Ag + (size_t)row * HH + c * 4);
    }
  };
  auto issueB = [&](int kt, int buf) {
    const short* Bg = Bt + (size_t)n0 * HH + (size_t)(kt0 + kt) * 64;
#pragma unroll
    for (int i = 0; i < 4; ++i) {
      int slot = i * 256 + w * 64 + lane;
      int row = slot >> 3, c = slot & 7;
      int cs = c ^ (row & 7);
      GLOAD_LDS16(Bg + (size_t)row * HH + cs * 8,
                  (char*)&Bs[0][0][0] + (size_t)buf * 16384 + (size_t)(i * 256 + w * 64) * 16);
    }
  };
  auto writeA = [&]() {
#pragma unroll
    for (int i = 0; i < 8; ++i) {
      int slot = i * 256 + t;
      int row = slot >> 4, c = slot & 15;
      unsigned d0, d1;
      asm("v_cvt_pk_bf16_f32 %0, %1, %2" : "=v"(d0) : "v"(areg[i].x), "v"(areg[i].y));
      asm("v_cvt_pk_bf16_f32 %0, %1, %2" : "=v"(d1) : "v"(areg[i].z), "v"(areg[i].w));
      int phys = (c >> 1) ^ (row & 7);
      uint2 val = {d0, d1};
      *(uint2*)((char*)&As[0][0] + (size_t)row * 128 + phys * 16 + (c & 1) * 8) = val;
    }
  };
  auto compute = [&](int buf) {
#pragma unroll
    for (int kk = 0; kk < 2; ++kk) {
      s16x8 a[4], bb[4];
#pragma unroll
      for (int i = 0; i < 4; ++i) {
        int row = wm * 64 + i * 16 + (lane & 15);
        int p = (kk * 4 + (lane >> 4)) ^ (row & 7);
        a[i] = *(const s16x8*)((const char*)&As[0][0] + (size_t)row * 128 + p * 16);
      }
#pragma unroll
      for (int i = 0; i < 4; ++i) {
        int row = wn * 64 + i * 16 + (lane & 15);
        int p = (kk * 4 + (lane >> 4)) ^ (row & 7);
        bb[i] = *(const s16x8*)((const char*)&Bs[0][0][0] + (size_t)buf * 16384 + (size_t)row * 128 + p * 16);
      }
#pragma unroll
      for (int mi = 0; mi < 4; ++mi)
#pragma unroll
        for (int ni = 0; ni < 4; ++ni)
          acc[mi][ni] = __builtin_amdgcn_mfma_f32_16x16x32_bf16(a[mi], bb[ni], acc[mi][ni], 0, 0, 0);
    }
  };

  issueA(0); issueB(0, 0);
  writeA();
  __syncthreads();
  for (int kt = 0; kt < 3; ++kt) {
    if (kt + 1 < 3) { issueA(kt + 1); issueB(kt + 1, (kt + 1) & 1); }
    compute(kt & 1);
    __syncthreads();
    if (kt + 1 < 3) {
      writeA();
      __syncthreads();
    }
  }

  float* po = part + (size_t)blockIdx.y * 128 * HH;
#pragma unroll
  for (int mi = 0; mi < 4; ++mi) {
    int row = wm * 64 + mi * 16 + ((lane >> 4) * 4);
#pragma unroll
    for (int ni = 0; ni < 4; ++ni) {
      int col = n0 + wn * 64 + ni * 16 + (lane & 15);
#pragma unroll
      for (int j = 0; j < 4; ++j)
        po[(size_t)(row + j) * HH + col] = acc[mi][ni][j];
    }
  }
}

// ---------------------------------------------------------------- reduce partials -> agg (+bl), cvec
__global__ void k_red_agg(const float* __restrict__ part, const float* __restrict__ bl,
                          const float* __restrict__ bt, float* __restrict__ out,
                          float* __restrict__ cvec) {
  int row = blockIdx.x;
  int t = threadIdx.x;
  int lane = t & 63, w = t >> 6;
  __shared__ float wred[4];
  float dotbt = 0.f;
#pragma unroll
  for (int cc = 0; cc < 3; ++cc) {
    int c = cc * 256 + t;
    float s = bl[c];
#pragma unroll
    for (int kc = 0; kc < 4; ++kc)
      s += part[((size_t)kc * 128 + row) * HH + c];
    out[O_AGGL + (size_t)row * DD + c] = s;
    dotbt += s * bt[c];
  }
  for (int sh = 32; sh; sh >>= 1) dotbt += __shfl_xor(dotbt, sh, 64);
  if (lane == 0) wred[w] = dotbt;
  __syncthreads();
  if (t == 0) cvec[row] = wred[0] + wred[1] + wred[2] + wred[3];
}

// ---------------------------------------------------------------- fused scores+softmax-partial+pool
// Occupancy push: Bs stores only the 8 REAL qh rows (12.4 KB; rows 8..15 were
// zeros — 12.4 KB of dead LDS). B-fragment read masks rows >= 8 to zero in
// registers. LDS 50.4 KB -> 3 blocks/CU = 24 waves/CU (wave count is the
// measured lever for this L3-latency-bound kernel — r19/r20 evidence).
__global__ __launch_bounds__(512, 6)
void k_attnpool(const float* __restrict__ hs, const float* __restrict__ qhp,
                const float* __restrict__ cvec, const int* __restrict__ lmask,
                const int* __restrict__ amask, const float* __restrict__ temp_p,
                short* __restrict__ part_o, float* __restrict__ part_ml) {
  __shared__ short As[8][2][16][64];  // wave-private double buffers, 32 KB
  __shared__ short Bs[8][776];        // 12.4 KB (real qh rows only)
  __shared__ float w_acc[4][64][4];   // 4 KB split-K combine
  __shared__ float w_lds[64][8];      // 2 KB
  int chunk = blockIdx.x;             // 32
  int b = blockIdx.y;                 // 16
  int t = threadIdx.x;
  int lane = t & 63, w = t >> 6;      // w 0..7
  int wq = w & 3, kw = w >> 2;        // token quad, K-half

  // stage qh = sum of 4 split-K partials (L2-hot), bf16
  for (int c = t; c < HH; c += 512) {
#pragma unroll
    for (int r = 0; r < 8; ++r) {
      size_t o = (size_t)(b * MM + r) * HH + c;
      float s = qhp[o] + qhp[(size_t)128 * HH + o] + qhp[(size_t)256 * HH + o] + qhp[(size_t)384 * HH + o];
      Bs[r][c] = f2bf(s);
    }
  }

  const float* Hg = hs + (size_t)(b * LL + chunk * 64) * HH;
  const float* Wrow = Hg + (size_t)(wq * 16) * HH;   // this wave's 16 token rows
  int kbase = kw * 384;                              // this wave's K-half
  bool brow_ok = (lane & 15) < MM;
  float4 areg[2][4];

  auto issueA = [&](int set, int kt) {
#pragma unroll
    for (int i = 0; i < 4; ++i) {
      int slot = i * 64 + lane;
      int row = slot >> 4, c = slot & 15;
      if (set == 0)
        areg[0][i] = *(const float4*)(Wrow + (size_t)row * HH + kbase + kt * 64 + c * 4);
      else
        areg[1][i] = *(const float4*)(Wrow + (size_t)row * HH + kbase + kt * 64 + c * 4);
    }
  };
  auto writeA = [&](int set, int buf) {
#pragma unroll
    for (int i = 0; i < 4; ++i) {
      int slot = i * 64 + lane;
      int row = slot >> 4, c = slot & 15;
      float4 v = set == 0 ? areg[0][i] : areg[1][i];
      unsigned d0, d1;
      asm("v_cvt_pk_bf16_f32 %0, %1, %2" : "=v"(d0) : "v"(v.x), "v"(v.y));
      asm("v_cvt_pk_bf16_f32 %0, %1, %2" : "=v"(d1) : "v"(v.z), "v"(v.w));
      int phys = (c >> 1) ^ (row & 7);
      uint2 val = {d0, d1};
      *(uint2*)((char*)&As[w][buf][0][0] + (size_t)row * 128 + phys * 16 + (c & 1) * 8) = val;
    }
  };

  f32x4 acc = {};
  issueA(0, 0); issueA(1, 1);
  writeA(0, 0);
  __syncthreads();                     // Bs visible (As slices wave-private)
#pragma unroll
  for (int kt = 0; kt < 6; ++kt) {
    int buf = kt & 1;
#pragma unroll
    for (int kk = 0; kk < 2; ++kk) {
      int r = lane & 15;
      int p = (kk * 4 + (lane >> 4)) ^ (r & 7);
      s16x8 a = *(const s16x8*)((const char*)&As[w][buf][0][0] + (size_t)r * 128 + p * 16);
      s16x8 braw = *(const s16x8*)&Bs[r & 7][kbase + kt * 64 + kk * 32 + (lane >> 4) * 8];
      s16x8 bfr = brow_ok ? braw : (s16x8){0, 0, 0, 0, 0, 0, 0, 0};
      acc = __builtin_amdgcn_mfma_f32_16x16x32_bf16(a, bfr, acc, 0, 0, 0);
    }
    if (kt + 1 < 6) writeA((kt + 1) & 1, (kt + 1) & 1);
    if (kt + 2 < 6) issueA(kt & 1, kt + 2);
  }

  // combine K-halves: waves 4..7 deposit, waves 0..3 add
  if (kw == 1) {
    w_acc[wq][lane][0] = acc[0]; w_acc[wq][lane][1] = acc[1];
    w_acc[wq][lane][2] = acc[2]; w_acc[wq][lane][3] = acc[3];
  }
  __syncthreads();
  if (kw == 0) {
    acc[0] += w_acc[wq][lane][0]; acc[1] += w_acc[wq][lane][1];
    acc[2] += w_acc[wq][lane][2]; acc[3] += w_acc[wq][lane][3];
  }

  // epilogue (waves 0..3) -> s in LDS
  float inv_temp = 1.0f / fmaxf(fabsf(temp_p[0]), 0.1f);
  int m = lane & 15;
  int tok0 = wq * 16 + (lane >> 4) * 4;
  if (kw == 0 && m < MM) {
    float cv = cvec[b * MM + m];
    int4 lm = *(const int4*)&lmask[b * LL + chunk * 64 + tok0];
    int4 am = *(const int4*)&amask[b * LL + chunk * 64 + tok0];
    w_lds[tok0 + 0][m] = (lm.x == 0 && am.x == 1) ? (acc[0] + cv) * inv_temp : -1e30f;
    w_lds[tok0 + 1][m] = (lm.y == 0 && am.y == 1) ? (acc[1] + cv) * inv_temp : -1e30f;
    w_lds[tok0 + 2][m] = (lm.z == 0 && am.z == 1) ? (acc[2] + cv) * inv_temp : -1e30f;
    w_lds[tok0 + 3][m] = (lm.w == 0 && am.w == 1) ? (acc[3] + cv) * inv_temp : -1e30f;
  }
  __syncthreads();

  // Phase 2: wave w handles m = w (one token per lane, single pass)
  {
    float v = w_lds[lane][w];
    float mx = v;
    for (int s = 32; s; s >>= 1) mx = fmaxf(mx, __shfl_xor(mx, s, 64));
    float e = __expf(v - mx);
    float l = e;
    for (int s = 32; s; s >>= 1) l += __shfl_xor(l, s, 64);
    w_lds[lane][w] = e;
    if (lane == 0) {
      float* pml = part_ml + ((size_t)(chunk * BB + b) * MM + w) * 2;
      pml[0] = mx; pml[1] = l;
    }
  }
  __syncthreads();

  // Phase 3: partial pool; threads 0..383 own 2 h-cols each; bf16 po output.
  if (t < 384) {
    int h0 = t * 2;
    float2 o[8] = {};
    const float* hp = Hg + h0;
#pragma unroll 4
    for (int tok = 0; tok < 64; ++tok) {
      float2 hv = *(const float2*)(hp + (size_t)tok * HH);
      float4 w0 = *(const float4*)&w_lds[tok][0];
      float4 w1 = *(const float4*)&w_lds[tok][4];
      o[0].x += w0.x * hv.x; o[0].y += w0.x * hv.y;
      o[1].x += w0.y * hv.x; o[1].y += w0.y * hv.y;
      o[2].x += w0.z * hv.x; o[2].y += w0.z * hv.y;
      o[3].x += w0.w * hv.x; o[3].y += w0.w * hv.y;
      o[4].x += w1.x * hv.x; o[4].y += w1.x * hv.y;
      o[5].x += w1.y * hv.x; o[5].y += w1.y * hv.y;
      o[6].x += w1.z * hv.x; o[6].y += w1.z * hv.y;
      o[7].x += w1.w * hv.x; o[7].y += w1.w * hv.y;
    }
    short* po = part_o + (size_t)(chunk * BB + b) * MM * HH + h0;
#pragma unroll
    for (int mm = 0; mm < 8; ++mm) {
      short2 pv = {f2bf(o[mm].x), f2bf(o[mm].y)};
      *(short2*)(po + (size_t)mm * HH) = pv;
    }
  }
}

// ---------------------------------------------------------------- finish: flash-reduce partials -> hst
__global__ void k_finish(const short* __restrict__ part_o, const float* __restrict__ part_ml,
                         float* __restrict__ hst) {
  int row = blockIdx.x;
  int b = row >> 3, m = row & 7;
  int t = threadIdx.x;     // 192
  float mg = -1e30f;
#pragma unroll
  for (int lc = 0; lc < NCH; ++lc)
    mg = fmaxf(mg, part_ml[((size_t)(lc * BB + b) * MM + m) * 2]);
  float L = 0.f;
  f32x4 acc = {};
  int h0 = t * 4;
#pragma unroll 4
  for (int lc = 0; lc < NCH; ++lc) {
    const float* pml = part_ml + ((size_t)(lc * BB + b) * MM + m) * 2;
    float f = __expf(pml[0] - mg);
    L += pml[1] * f;
    s16x4 v = *(const s16x4*)(part_o + ((size_t)(lc * BB + b) * MM + m) * HH + h0);
    acc[0] += bf2f(v[0]) * f; acc[1] += bf2f(v[1]) * f;
    acc[2] += bf2f(v[2]) * f; acc[3] += bf2f(v[3]) * f;
  }
  float inv = 1.0f / L;
  f32x4 r = {acc[0] * inv, acc[1] * inv, acc[2] * inv, acc[3] * inv};
  *(f32x4*)(hst + (size_t)row * HH + h0) = r;
}

// ---------------------------------------------------------------- head: aggt reduce + write + cosine
__global__ void k_head(const float* __restrict__ part, const float* __restrict__ bt,
                       const float* __restrict__ lscale_p, float* __restrict__ out) {
  int row = blockIdx.x;   // 128
  int lane = threadIdx.x; // 64
  const float* al = out + O_AGGL + (size_t)row * DD;
  float dot = 0.f, nt = 0.f, nl = 0.f;
  for (int i = lane; i < DD; i += 64) {
    float a = bt[i];
#pragma unroll
    for (int kc = 0; kc < 4; ++kc)
      a += part[((size_t)kc * 128 + row) * HH + i];
    out[O_AGGT + (size_t)row * DD + i] = a;
    float c = al[i];
    dot += a * c; nt += a * a; nl += c * c;
  }
  for (int s = 32; s; s >>= 1) {
    dot += __shfl_xor(dot, s, 64);
    nt  += __shfl_xor(nt, s, 64);
    nl  += __shfl_xor(nl, s, 64);
  }
  if (lane == 0) {
    float scale = expf(lscale_p[0]);
    float denom = fmaxf(sqrtf(nt), 1e-8f) * fmaxf(sqrtf(nl), 1e-8f);
    out[O_LOGITS + row] = dot / denom * scale;
    out[O_BID + row] = (float)(row >> 3);
    out[O_LID + row] = (float)((row & 7) + 1);
    if (row == 0) out[O_SCALE] = scale;
  }
}

extern "C" void kernel_launch(void* const* d_in, const int* in_sizes, int n_in,
                              void* d_out, int out_size, void* d_ws, size_t ws_size,
                              hipStream_t stream) {
  const float* hs    = (const float*)d_in[0];
  const float* Wt    = (const float*)d_in[1];
  const float* bt    = (const float*)d_in[2];
  const float* Wl    = (const float*)d_in[3];
  const float* bl    = (const float*)d_in[4];
  const float* atemp = (const float*)d_in[5];
  const float* lsc   = (const float*)d_in[6];
  const int*   lmask = (const int*)d_in[7];
  const int*   amask = (const int*)d_in[9];
  float* out = (float*)d_out;
  char* ws = (char*)d_ws;
  short* Wtt  = (short*)(ws + WTT_OFF);
  short* Wlt  = (short*)(ws + WLT_OFF);
  short* Wtb  = (short*)(ws + WTB_OFF);
  float* hbar = (float*)(ws + HBAR_OFF);
  float* hst  = (float*)(ws + HST_OFF);
  float* cvec = (float*)(ws + CVEC_OFF);
  float* pml  = (float*)(ws + PML_OFF);
  short* po   = (short*)(ws + PO_OFF);
  float* skp  = (float*)(ws + SK_OFF);

  k_prep<<<560, 256, 0, stream>>>(Wt, Wl, Wtt, Wlt, Wtb, hs, lmask, hbar);
  k_skgemm<<<dim3(6, 4), 256, 0, stream>>>(hbar, Wlt, skp);
  k_red_agg<<<128, 256, 0, stream>>>(skp, bl, bt, out, cvec);
  k_skgemm<<<dim3(6, 4), 256, 0, stream>>>(out + O_AGGL, Wtb, skp);
  k_attnpool<<<dim3(NCH, 16), 512, 0, stream>>>(hs, skp, cvec, lmask, amask, atemp, po, pml);
  k_finish<<<128, 192, 0, stream>>>(po, pml, hst);
  k_skgemm<<<dim3(6, 4), 256, 0, stream>>>(hst, Wtt, skp);
  k_head<<<128, 64, 0, stream>>>(skp, bt, lsc, out);
}

// Round 23
// 83.438 us; speedup vs baseline: 1.0264x; 1.0006x over previous
//
#include <hip/hip_runtime.h>
#include <hip/hip_bf16.h>

typedef __attribute__((ext_vector_type(8))) short s16x8;
typedef __attribute__((ext_vector_type(4))) short s16x4;
typedef __attribute__((ext_vector_type(4))) float f32x4;

#define BB 16
#define LL 2048
#define HH 768
#define DD 768
#define MM 8
#define TOKS 32          // attnpool tokens per chunk
#define NCH 64           // attnpool chunks (1024 blocks, 2/CU)

// d_out layout (float elements)
#define O_LOGITS 0
#define O_BID    128
#define O_LID    256
#define O_AGGL   384
#define O_SCALE  98688
#define O_AGGT   98689

// ws layout (bytes)
#define WTT_OFF  0u          // Wt^T bf16 768*768*2
#define WLT_OFF  1179648u    // Wl^T bf16
#define WTB_OFF  2359296u    // Wt bf16 (natural)
#define HBAR_OFF 3538944u    // 128*768 fp32
#define HST_OFF  4325376u    // 128*768 fp32
#define CVEC_OFF 4718592u    // 128 fp32
#define PML_OFF  4719104u    // 64*16*8*2 fp32 = 65536
#define PO_OFF   4784640u    // 64*16*8*768 bf16 = 12582912
#define SK_OFF   17367552u   // 4*128*768 fp32 (split-K partials, reused)

__device__ __forceinline__ short f2bf(float x) {
  union { float f; unsigned u; } v; v.f = x;
  unsigned r = v.u + 0x7FFFu + ((v.u >> 16) & 1u);
  return (short)(r >> 16);
}
__device__ __forceinline__ float bf2f(short x) {
  union { unsigned u; float f; } v; v.u = ((unsigned)(unsigned short)x) << 16;
  return v.f;
}

// async global->LDS, 16B per lane; LDS dest is wave-uniform base (HW adds lane*16)
#define GLOAD_LDS16(gp, lp) __builtin_amdgcn_global_load_lds( \
    (const __attribute__((address_space(1))) unsigned int*)(gp), \
    (__attribute__((address_space(3))) unsigned int*)(lp), 16, 0, 0)

// ---------------------------------------------------------------- prep: W converts + hbar (fused)
__global__ void k_prep(const float* __restrict__ Wt, const float* __restrict__ Wl,
                       short* __restrict__ Wtt, short* __restrict__ Wlt,
                       short* __restrict__ Wtb,
                       const float* __restrict__ hs, const int* __restrict__ lmask,
                       float* __restrict__ hbar) {
  __shared__ float tile[64][65];
  __shared__ int list[LL];
  __shared__ int nlist_s;
  int bx = blockIdx.x;
  int t = threadIdx.x;
  if (bx < 432) {
    int z = bx / 144, r = bx % 144;
    int kb = (r % 12) * 64, nb = (r / 12) * 64;
    int c = t & 63;
    int r0 = (t >> 6) * 16;
    if (z == 2) {
#pragma unroll
      for (int i = 0; i < 16; ++i) {
        int rr = kb + r0 + i;
        Wtb[(size_t)rr * DD + nb + c] = f2bf(Wt[(size_t)rr * DD + nb + c]);
      }
      return;
    }
    const float* src = z ? Wl : Wt;
    short* dst = z ? Wlt : Wtt;
#pragma unroll
    for (int i = 0; i < 16; ++i)
      tile[r0 + i][c] = src[(size_t)(kb + r0 + i) * DD + nb + c];
    __syncthreads();
#pragma unroll
    for (int i = 0; i < 16; ++i)
      dst[(size_t)(nb + r0 + i) * HH + kb + c] = f2bf(tile[c][r0 + i]);
    return;
  }
  int bh = bx - 432;
  int b = bh >> 3, m = bh & 7;
  int lane = t & 63, w = t >> 6;
  if (w == 0) {                       // deterministic compaction
    int base = 0;
    for (int win = 0; win < LL / 64; ++win) {
      int l = win * 64 + lane;
      bool match = (lmask[b * LL + l] == m + 1);
      unsigned long long mk = __ballot(match);
      if (match) {
        int pos = base + (int)__popcll(mk & ((1ull << lane) - 1ull));
        list[pos] = l;
      }
      base += (int)__popcll(mk);
    }
    if (lane == 0) nlist_s = base;
  }
  __syncthreads();
  int n = nlist_s;
  float inv = 1.0f / (float)(n > 1 ? n : 1);
  float a0 = 0.f, a1 = 0.f, a2 = 0.f;
  for (int i = 0; i < n; ++i) {
    const float* rr = hs + (size_t)(b * LL + list[i]) * HH;
    a0 += rr[t]; a1 += rr[t + 256]; a2 += rr[t + 512];
  }
  float* dst = hbar + (size_t)(b * MM + m) * HH;
  dst[t] = a0 * inv; dst[t + 256] = a1 * inv; dst[t + 512] = a2 * inv;
}

// ---------------------------------------------------------------- split-K 128x768 GEMM (K=768/4)
__global__ __launch_bounds__(256, 3)
void k_skgemm(const float* __restrict__ A, const short* __restrict__ Bt,
              float* __restrict__ part) {
  __shared__ short As[128][64];
  __shared__ short Bs[2][128][64];
  int t = threadIdx.x;
  int lane = t & 63, w = t >> 6;
  int wm = w >> 1, wn = w & 1;
  int n0 = blockIdx.x * 128;
  int kt0 = blockIdx.y * 3;

  f32x4 acc[4][4] = {};
  float4 areg[8];

  auto issueA = [&](int kt) {
    const float* Ag = A + (size_t)(kt0 + kt) * 64;
#pragma unroll
    for (int i = 0; i < 8; ++i) {
      int slot = i * 256 + t;
      int row = slot >> 4, c = slot & 15;
      areg[i] = *(const float4*)(Ag + (size_t)row * HH + c * 4);
    }
  };
  auto issueB = [&](int kt, int buf) {
    const short* Bg = Bt + (size_t)n0 * HH + (size_t)(kt0 + kt) * 64;
#pragma unroll
    for (int i = 0; i < 4; ++i) {
      int slot = i * 256 + w * 64 + lane;
      int row = slot >> 3, c = slot & 7;
      int cs = c ^ (row & 7);
      GLOAD_LDS16(Bg + (size_t)row * HH + cs * 8,
                  (char*)&Bs[0][0][0] + (size_t)buf * 16384 + (size_t)(i * 256 + w * 64) * 16);
    }
  };
  auto writeA = [&]() {
#pragma unroll
    for (int i = 0; i < 8; ++i) {
      int slot = i * 256 + t;
      int row = slot >> 4, c = slot & 15;
      unsigned d0, d1;
      asm("v_cvt_pk_bf16_f32 %0, %1, %2" : "=v"(d0) : "v"(areg[i].x), "v"(areg[i].y));
      asm("v_cvt_pk_bf16_f32 %0, %1, %2" : "=v"(d1) : "v"(areg[i].z), "v"(areg[i].w));
      int phys = (c >> 1) ^ (row & 7);
      uint2 val = {d0, d1};
      *(uint2*)((char*)&As[0][0] + (size_t)row * 128 + phys * 16 + (c & 1) * 8) = val;
    }
  };
  auto compute = [&](int buf) {
#pragma unroll
    for (int kk = 0; kk < 2; ++kk) {
      s16x8 a[4], bb[4];
#pragma unroll
      for (int i = 0; i < 4; ++i) {
        int row = wm * 64 + i * 16 + (lane & 15);
        int p = (kk * 4 + (lane >> 4)) ^ (row & 7);
        a[i] = *(const s16x8*)((const char*)&As[0][0] + (size_t)row * 128 + p * 16);
      }
#pragma unroll
      for (int i = 0; i < 4; ++i) {
        int row = wn * 64 + i * 16 + (lane & 15);
        int p = (kk * 4 + (lane >> 4)) ^ (row & 7);
        bb[i] = *(const s16x8*)((const char*)&Bs[0][0][0] + (size_t)buf * 16384 + (size_t)row * 128 + p * 16);
      }
#pragma unroll
      for (int mi = 0; mi < 4; ++mi)
#pragma unroll
        for (int ni = 0; ni < 4; ++ni)
          acc[mi][ni] = __builtin_amdgcn_mfma_f32_16x16x32_bf16(a[mi], bb[ni], acc[mi][ni], 0, 0, 0);
    }
  };

  issueA(0); issueB(0, 0);
  writeA();
  __syncthreads();
  for (int kt = 0; kt < 3; ++kt) {
    if (kt + 1 < 3) { issueA(kt + 1); issueB(kt + 1, (kt + 1) & 1); }
    compute(kt & 1);
    __syncthreads();
    if (kt + 1 < 3) {
      writeA();
      __syncthreads();
    }
  }

  float* po = part + (size_t)blockIdx.y * 128 * HH;
#pragma unroll
  for (int mi = 0; mi < 4; ++mi) {
    int row = wm * 64 + mi * 16 + ((lane >> 4) * 4);
#pragma unroll
    for (int ni = 0; ni < 4; ++ni) {
      int col = n0 + wn * 64 + ni * 16 + (lane & 15);
#pragma unroll
      for (int j = 0; j < 4; ++j)
        po[(size_t)(row + j) * HH + col] = acc[mi][ni][j];
    }
  }
}

// ---------------------------------------------------------------- reduce partials -> agg (+bl), cvec
__global__ void k_red_agg(const float* __restrict__ part, const float* __restrict__ bl,
                          const float* __restrict__ bt, float* __restrict__ out,
                          float* __restrict__ cvec) {
  int row = blockIdx.x;
  int t = threadIdx.x;
  int lane = t & 63, w = t >> 6;
  __shared__ float wred[4];
  float dotbt = 0.f;
#pragma unroll
  for (int cc = 0; cc < 3; ++cc) {
    int c = cc * 256 + t;
    float s = bl[c];
#pragma unroll
    for (int kc = 0; kc < 4; ++kc)
      s += part[((size_t)kc * 128 + row) * HH + c];
    out[O_AGGL + (size_t)row * DD + c] = s;
    dotbt += s * bt[c];
  }
  for (int sh = 32; sh; sh >>= 1) dotbt += __shfl_xor(dotbt, sh, 64);
  if (lane == 0) wred[w] = dotbt;
  __syncthreads();
  if (t == 0) cvec[row] = wred[0] + wred[1] + wred[2] + wred[3];
}

// ---------------------------------------------------------------- fused scores+softmax-partial+pool
// SINGLE hs READ: whole 32x768 chunk staged once as swizzled bf16 in LDS;
// phase 1 = pure-LDS MFMA (2 token-groups x 4 K-quarters); phase 3 pools from
// LDS (no L3 re-read — halves the attnpool L3 stream that r20/r22 counters
// identified as the cost). 67 KB LDS -> 2 blocks/CU.
__global__ __launch_bounds__(512, 4)
void k_attnpool(const float* __restrict__ hs, const float* __restrict__ qhp,
                const float* __restrict__ cvec, const int* __restrict__ lmask,
                const int* __restrict__ amask, const float* __restrict__ temp_p,
                short* __restrict__ part_o, float* __restrict__ part_ml) {
  __shared__ short Hs[TOKS][768];     // 48 KB, 16B-chunk XOR swizzle per row
  __shared__ short Bs[8][776];        // 12.4 KB (real qh rows only)
  __shared__ float w_acc[2][3][64][4];// 6 KB split-K combine
  __shared__ float w_lds[TOKS][8];    // 1 KB
  int chunk = blockIdx.x;             // 64 chunks of 32 tokens
  int b = blockIdx.y;                 // 16
  int t = threadIdx.x;
  int lane = t & 63, w = t >> 6;      // w 0..7
  int tq = w & 1, kq = w >> 1;        // token group (16), K-quarter (192)

  // stage qh = sum of 4 split-K partials (L2-hot), bf16
  for (int c = t; c < HH; c += 512) {
#pragma unroll
    for (int r = 0; r < 8; ++r) {
      size_t o = (size_t)(b * MM + r) * HH + c;
      float s = qhp[o] + qhp[(size_t)128 * HH + o] + qhp[(size_t)256 * HH + o] + qhp[(size_t)384 * HH + o];
      Bs[r][c] = f2bf(s);
    }
  }

  // stage hs chunk once: 32 rows x 96 16B-chunks, phys = c ^ (row&7)
  const float* Hg = hs + (size_t)(b * LL + chunk * TOKS) * HH;
#pragma unroll
  for (int i = 0; i < 6; ++i) {
    int slot = i * 512 + t;           // 3072 chunks
    int row = slot / 96, c = slot % 96;
    const float* src = Hg + (size_t)row * HH + c * 8;
    float4 x0 = *(const float4*)src;
    float4 x1 = *(const float4*)(src + 4);
    unsigned d0, d1, d2, d3;
    asm("v_cvt_pk_bf16_f32 %0, %1, %2" : "=v"(d0) : "v"(x0.x), "v"(x0.y));
    asm("v_cvt_pk_bf16_f32 %0, %1, %2" : "=v"(d1) : "v"(x0.z), "v"(x0.w));
    asm("v_cvt_pk_bf16_f32 %0, %1, %2" : "=v"(d2) : "v"(x1.x), "v"(x1.y));
    asm("v_cvt_pk_bf16_f32 %0, %1, %2" : "=v"(d3) : "v"(x1.z), "v"(x1.w));
    int phys = c ^ (row & 7);
    uint4 val = {d0, d1, d2, d3};
    *(uint4*)((char*)&Hs[0][0] + (size_t)row * 1536 + phys * 16) = val;
  }
  __syncthreads();                    // Hs + Bs visible

  // Phase 1: pure-LDS MFMA. Wave = (tq, kq): 16 tokens x 192 K (3 steps of 64).
  bool brow_ok = (lane & 15) < MM;
  int arow = tq * 16 + (lane & 15);
  f32x4 acc = {};
#pragma unroll
  for (int kt = 0; kt < 3; ++kt) {
#pragma unroll
    for (int kk = 0; kk < 2; ++kk) {
      int c = kq * 24 + kt * 8 + kk * 4 + (lane >> 4);
      int phys = c ^ (arow & 7);
      s16x8 a = *(const s16x8*)((const char*)&Hs[0][0] + (size_t)arow * 1536 + phys * 16);
      int koff = kq * 192 + kt * 64 + kk * 32 + (lane >> 4) * 8;
      s16x8 braw = *(const s16x8*)&Bs[(lane & 15) & 7][koff];
      s16x8 bfr = brow_ok ? braw : (s16x8){0, 0, 0, 0, 0, 0, 0, 0};
      acc = __builtin_amdgcn_mfma_f32_16x16x32_bf16(a, bfr, acc, 0, 0, 0);
    }
  }

  // combine K-quarters: kq 1..3 deposit, kq 0 adds
  if (kq > 0) {
    w_acc[tq][kq - 1][lane][0] = acc[0]; w_acc[tq][kq - 1][lane][1] = acc[1];
    w_acc[tq][kq - 1][lane][2] = acc[2]; w_acc[tq][kq - 1][lane][3] = acc[3];
  }
  __syncthreads();
  if (kq == 0) {
#pragma unroll
    for (int q = 0; q < 3; ++q) {
      acc[0] += w_acc[tq][q][lane][0]; acc[1] += w_acc[tq][q][lane][1];
      acc[2] += w_acc[tq][q][lane][2]; acc[3] += w_acc[tq][q][lane][3];
    }
  }

  // epilogue (kq==0 waves) -> s in LDS
  float inv_temp = 1.0f / fmaxf(fabsf(temp_p[0]), 0.1f);
  int m = lane & 15;
  int tok0 = tq * 16 + (lane >> 4) * 4;
  if (kq == 0 && m < MM) {
    float cv = cvec[b * MM + m];
    int4 lm = *(const int4*)&lmask[b * LL + chunk * TOKS + tok0];
    int4 am = *(const int4*)&amask[b * LL + chunk * TOKS + tok0];
    w_lds[tok0 + 0][m] = (lm.x == 0 && am.x == 1) ? (acc[0] + cv) * inv_temp : -1e30f;
    w_lds[tok0 + 1][m] = (lm.y == 0 && am.y == 1) ? (acc[1] + cv) * inv_temp : -1e30f;
    w_lds[tok0 + 2][m] = (lm.z == 0 && am.z == 1) ? (acc[2] + cv) * inv_temp : -1e30f;
    w_lds[tok0 + 3][m] = (lm.w == 0 && am.w == 1) ? (acc[3] + cv) * inv_temp : -1e30f;
  }
  __syncthreads();

  // Phase 2: wave w handles m = w; tokens on lanes 0..31
  {
    float v = (lane < TOKS) ? w_lds[lane][w] : -1e30f;
    float mx = v;
    for (int s = 32; s; s >>= 1) mx = fmaxf(mx, __shfl_xor(mx, s, 64));
    float e = (lane < TOKS) ? __expf(v - mx) : 0.f;
    float l = e;
    for (int s = 32; s; s >>= 1) l += __shfl_xor(l, s, 64);
    if (lane < TOKS) w_lds[lane][w] = e;
    if (lane == 0) {
      float* pml = part_ml + ((size_t)(chunk * BB + b) * MM + w) * 2;
      pml[0] = mx; pml[1] = l;
    }
  }
  __syncthreads();

  // Phase 3: pool from LDS (bf16 hs); threads 0..383 own 2 h-cols each
  if (t < 384) {
    int cch = t >> 2;                 // 16B chunk = (t*2)/8
    int within = ((t * 2) & 7) * 2;   // byte offset inside chunk
    float2 o[8] = {};
#pragma unroll 4
    for (int tok = 0; tok < TOKS; ++tok) {
      int phys = cch ^ (tok & 7);
      unsigned pv = *(const unsigned*)((const char*)&Hs[0][0] + (size_t)tok * 1536 + phys * 16 + within);
      float hx = bf2f((short)(pv & 0xffff));
      float hy = bf2f((short)(pv >> 16));
      float4 w0 = *(const float4*)&w_lds[tok][0];
      float4 w1 = *(const float4*)&w_lds[tok][4];
      o[0].x += w0.x * hx; o[0].y += w0.x * hy;
      o[1].x += w0.y * hx; o[1].y += w0.y * hy;
      o[2].x += w0.z * hx; o[2].y += w0.z * hy;
      o[3].x += w0.w * hx; o[3].y += w0.w * hy;
      o[4].x += w1.x * hx; o[4].y += w1.x * hy;
      o[5].x += w1.y * hx; o[5].y += w1.y * hy;
      o[6].x += w1.z * hx; o[6].y += w1.z * hy;
      o[7].x += w1.w * hx; o[7].y += w1.w * hy;
    }
    int h0 = t * 2;
    short* po = part_o + (size_t)(chunk * BB + b) * MM * HH + h0;
#pragma unroll
    for (int mm = 0; mm < 8; ++mm) {
      short2 pv = {f2bf(o[mm].x), f2bf(o[mm].y)};
      *(short2*)(po + (size_t)mm * HH) = pv;
    }
  }
}

// ---------------------------------------------------------------- finish: flash-reduce partials -> hst
__global__ void k_finish(const short* __restrict__ part_o, const float* __restrict__ part_ml,
                         float* __restrict__ hst) {
  int row = blockIdx.x;
  int b = row >> 3, m = row & 7;
  int t = threadIdx.x;     // 192
  float mg = -1e30f;
#pragma unroll
  for (int lc = 0; lc < NCH; ++lc)
    mg = fmaxf(mg, part_ml[((size_t)(lc * BB + b) * MM + m) * 2]);
  float L = 0.f;
  f32x4 acc = {};
  int h0 = t * 4;
#pragma unroll 4
  for (int lc = 0; lc < NCH; ++lc) {
    const float* pml = part_ml + ((size_t)(lc * BB + b) * MM + m) * 2;
    float f = __expf(pml[0] - mg);
    L += pml[1] * f;
    s16x4 v = *(const s16x4*)(part_o + ((size_t)(lc * BB + b) * MM + m) * HH + h0);
    acc[0] += bf2f(v[0]) * f; acc[1] += bf2f(v[1]) * f;
    acc[2] += bf2f(v[2]) * f; acc[3] += bf2f(v[3]) * f;
  }
  float inv = 1.0f / L;
  f32x4 r = {acc[0] * inv, acc[1] * inv, acc[2] * inv, acc[3] * inv};
  *(f32x4*)(hst + (size_t)row * HH + h0) = r;
}

// ---------------------------------------------------------------- head: aggt reduce + write + cosine
__global__ void k_head(const float* __restrict__ part, const float* __restrict__ bt,
                       const float* __restrict__ lscale_p, float* __restrict__ out) {
  int row = blockIdx.x;   // 128
  int lane = threadIdx.x; // 64
  const float* al = out + O_AGGL + (size_t)row * DD;
  float dot = 0.f, nt = 0.f, nl = 0.f;
  for (int i = lane; i < DD; i += 64) {
    float a = bt[i];
#pragma unroll
    for (int kc = 0; kc < 4; ++kc)
      a += part[((size_t)kc * 128 + row) * HH + i];
    out[O_AGGT + (size_t)row * DD + i] = a;
    float c = al[i];
    dot += a * c; nt += a * a; nl += c * c;
  }
  for (int s = 32; s; s >>= 1) {
    dot += __shfl_xor(dot, s, 64);
    nt  += __shfl_xor(nt, s, 64);
    nl  += __shfl_xor(nl, s, 64);
  }
  if (lane == 0) {
    float scale = expf(lscale_p[0]);
    float denom = fmaxf(sqrtf(nt), 1e-8f) * fmaxf(sqrtf(nl), 1e-8f);
    out[O_LOGITS + row] = dot / denom * scale;
    out[O_BID + row] = (float)(row >> 3);
    out[O_LID + row] = (float)((row & 7) + 1);
    if (row == 0) out[O_SCALE] = scale;
  }
}

extern "C" void kernel_launch(void* const* d_in, const int* in_sizes, int n_in,
                              void* d_out, int out_size, void* d_ws, size_t ws_size,
                              hipStream_t stream) {
  const float* hs    = (const float*)d_in[0];
  const float* Wt    = (const float*)d_in[1];
  const float* bt    = (const float*)d_in[2];
  const float* Wl    = (const float*)d_in[3];
  const float* bl    = (const float*)d_in[4];
  const float* atemp = (const float*)d_in[5];
  const float* lsc   = (const float*)d_in[6];
  const int*   lmask = (const int*)d_in[7];
  const int*   amask = (const int*)d_in[9];
  float* out = (float*)d_out;
  char* ws = (char*)d_ws;
  short* Wtt  = (short*)(ws + WTT_OFF);
  short* Wlt  = (short*)(ws + WLT_OFF);
  short* Wtb  = (short*)(ws + WTB_OFF);
  float* hbar = (float*)(ws + HBAR_OFF);
  float* hst  = (float*)(ws + HST_OFF);
  float* cvec = (float*)(ws + CVEC_OFF);
  float* pml  = (float*)(ws + PML_OFF);
  short* po   = (short*)(ws + PO_OFF);
  float* skp  = (float*)(ws + SK_OFF);

  k_prep<<<560, 256, 0, stream>>>(Wt, Wl, Wtt, Wlt, Wtb, hs, lmask, hbar);
  k_skgemm<<<dim3(6, 4), 256, 0, stream>>>(hbar, Wlt, skp);
  k_red_agg<<<128, 256, 0, stream>>>(skp, bl, bt, out, cvec);
  k_skgemm<<<dim3(6, 4), 256, 0, stream>>>(out + O_AGGL, Wtb, skp);
  k_attnpool<<<dim3(NCH, 16), 512, 0, stream>>>(hs, skp, cvec, lmask, amask, atemp, po, pml);
  k_finish<<<128, 192, 0, stream>>>(po, pml, hst);
  k_skgemm<<<dim3(6, 4), 256, 0, stream>>>(hst, Wtt, skp);
  k_head<<<128, 64, 0, stream>>>(skp, bt, lsc, out);
}